// Round 4
// baseline (397.713 us; speedup 1.0000x reference)
//
#include <hip/hip_runtime.h>
#include <cstdint>
#include <cstddef>

#define B_ 2
#define S_ 2048
#define HID_ 1024
#define H_ 16
#define DH_ 64

typedef __attribute__((ext_vector_type(8))) short short8;
typedef __attribute__((ext_vector_type(8))) unsigned short ushort8;
typedef __attribute__((ext_vector_type(4))) unsigned short ushort4v;
typedef __attribute__((ext_vector_type(4))) float floatx4;
typedef __attribute__((ext_vector_type(4))) float float4v;

static __device__ __forceinline__ unsigned short f2bf(float f) {
  unsigned int u = __float_as_uint(f);
  u += 0x7fffu + ((u >> 16) & 1u);
  return (unsigned short)(u >> 16);
}
static __device__ __forceinline__ float bf2f(unsigned short h) {
  return __uint_as_float(((unsigned int)h) << 16);
}

// ---------------------------------------------------------------------------
// Kernel 0: conversions. (unchanged, proven)
// ---------------------------------------------------------------------------
__global__ __launch_bounds__(256) void convert_kernel(
    const float* __restrict__ x, const float* __restrict__ w1,
    const float* __restrict__ w2, unsigned short* __restrict__ x_bf,
    unsigned short* __restrict__ w1t, unsigned short* __restrict__ w2t_hi,
    unsigned short* __restrict__ w2t_lo) {
  const int NX = B_ * S_ * HID_;
  const int NW = HID_ * HID_;
  int idx = blockIdx.x * 256 + threadIdx.x;
  if (idx < NX) {
    x_bf[idx] = f2bf(x[idx]);
  } else if (idx < NX + NW) {
    int i = idx - NX;
    int n = i >> 10, k = i & 1023;
    w1t[i] = f2bf(w1[k * HID_ + n]);
  } else if (idx < NX + 2 * NW) {
    int i = idx - NX - NW;
    int n = i >> 10, k = i & 1023;
    float v = w2[k * HID_ + n];
    unsigned short h = f2bf(v);
    w2t_hi[i] = h;
    w2t_lo[i] = f2bf(v - bf2f(h));
  }
}

// ---------------------------------------------------------------------------
// Kernel A: per-head QKV projection + bias + rotary. Emits split-bf16 for
// Q AND K (rotated, [h][s][128]) and transposed split-bf16 V ([h][d][S]).
// Same arithmetic values as the fp32-Q version (split of identical product).
// ---------------------------------------------------------------------------
__global__ __launch_bounds__(256) void qkv_kernel(
    const float* __restrict__ x, const float* __restrict__ wq,
    const float* __restrict__ bq, const float* __restrict__ wk,
    const float* __restrict__ bk, const float* __restrict__ wv,
    const float* __restrict__ theta,
    unsigned short* __restrict__ q_h, unsigned short* __restrict__ q_l,
    unsigned short* __restrict__ k_h, unsigned short* __restrict__ k_l,
    unsigned short* __restrict__ v_th, unsigned short* __restrict__ v_tl,
    int b) {
  __shared__ __align__(16) float xs[64 * 68];
  __shared__ __align__(16) float wqs[64 * 68];
  __shared__ __align__(16) float wks[64 * 68];
  __shared__ __align__(16) float wvs[64 * 68];

  int tid = threadIdx.x;
  int st = blockIdx.x, h = blockIdx.y;
  int s0 = st * 64;

#pragma unroll
  for (int i = 0; i < 4; ++i) {
    int cid = tid + i * 256;
    int r = cid >> 4, c4 = (cid & 15) * 4;
    *reinterpret_cast<float4v*>(&xs[r * 68 + c4]) =
        *reinterpret_cast<const float4v*>(x + ((size_t)(b * S_ + s0 + r)) * HID_ + h * DH_ + c4);
  }
#pragma unroll
  for (int i = 0; i < 4; ++i) {
    int cid = tid + i * 256;
    int d = cid >> 4, c4 = (cid & 15) * 4;
    *reinterpret_cast<float4v*>(&wqs[d * 68 + c4]) =
        *reinterpret_cast<const float4v*>(wq + (size_t)(h * DH_ + d) * DH_ + c4);
    *reinterpret_cast<float4v*>(&wks[d * 68 + c4]) =
        *reinterpret_cast<const float4v*>(wk + (size_t)(h * DH_ + d) * DH_ + c4);
    *reinterpret_cast<float4v*>(&wvs[d * 68 + c4]) =
        *reinterpret_cast<const float4v*>(wv + (size_t)(h * DH_ + d) * DH_ + c4);
  }
  __syncthreads();

  int rg = tid >> 3;
  int cg = tid & 7;
  int r0 = rg * 2, c0 = cg * 8;

  float aq[2][8], ak[2][8], av[2][8];
#pragma unroll
  for (int i = 0; i < 2; ++i)
#pragma unroll
    for (int j = 0; j < 8; ++j) { aq[i][j] = 0.f; ak[i][j] = 0.f; av[i][j] = 0.f; }

  for (int d = 0; d < 64; ++d) {
    float x0 = xs[(r0 + 0) * 68 + d];
    float x1 = xs[(r0 + 1) * 68 + d];
#pragma unroll
    for (int j = 0; j < 8; ++j) {
      float wqv = wqs[d * 68 + c0 + j];
      float wkv = wks[d * 68 + c0 + j];
      float wvv = wvs[d * 68 + c0 + j];
      aq[0][j] += x0 * wqv; aq[1][j] += x1 * wqv;
      ak[0][j] += x0 * wkv; ak[1][j] += x1 * wkv;
      av[0][j] += x0 * wvv; av[1][j] += x1 * wvv;
    }
  }

  float thv[8], bqv[8], bkv[8];
#pragma unroll
  for (int j = 0; j < 8; ++j) {
    thv[j] = theta[h * DH_ + c0 + j];
    bqv[j] = bq[h * DH_ + c0 + j];
    bkv[j] = bk[h * DH_ + c0 + j];
  }

  // Reuse xs/wqs LDS as bf16 V-transpose staging (all reads of them are done).
  __syncthreads();
  unsigned short* VtH = reinterpret_cast<unsigned short*>(xs);   // [64 d][72]
  unsigned short* VtL = reinterpret_cast<unsigned short*>(wqs);  // [64 d][72]

#pragma unroll
  for (int i = 0; i < 2; ++i) {
    int s = s0 + r0 + i;
    size_t qb = ((size_t)h * S_ + s) * 128;
    ushort8 qch, qcl, qsh, qsl, kch, kcl, ksh, ksl;
#pragma unroll
    for (int j = 0; j < 8; ++j) {
      float q = aq[i][j] + bqv[j];
      float k = ak[i][j] + bkv[j];
      float ang = (float)s * thv[j];
      float cs = cosf(ang), sn = sinf(ang);
      float qc = q * cs, qs = q * sn;
      unsigned short hq1 = f2bf(qc);
      qch[j] = hq1;
      qcl[j] = f2bf(qc - bf2f(hq1));
      unsigned short hq2 = f2bf(qs);
      qsh[j] = hq2;
      qsl[j] = f2bf(qs - bf2f(hq2));
      float kc = k * cs, ksn = k * sn;
      unsigned short h1 = f2bf(kc);
      kch[j] = h1;
      kcl[j] = f2bf(kc - bf2f(h1));
      unsigned short h2 = f2bf(ksn);
      ksh[j] = h2;
      ksl[j] = f2bf(ksn - bf2f(h2));
      float vv = av[i][j];
      unsigned short vh1 = f2bf(vv);
      VtH[(c0 + j) * 72 + (r0 + i)] = vh1;
      VtL[(c0 + j) * 72 + (r0 + i)] = f2bf(vv - bf2f(vh1));
    }
    *reinterpret_cast<ushort8*>(q_h + qb + c0) = qch;
    *reinterpret_cast<ushort8*>(q_h + qb + 64 + c0) = qsh;
    *reinterpret_cast<ushort8*>(q_l + qb + c0) = qcl;
    *reinterpret_cast<ushort8*>(q_l + qb + 64 + c0) = qsl;
    *reinterpret_cast<ushort8*>(k_h + qb + c0) = kch;
    *reinterpret_cast<ushort8*>(k_h + qb + 64 + c0) = ksh;
    *reinterpret_cast<ushort8*>(k_l + qb + c0) = kcl;
    *reinterpret_cast<ushort8*>(k_l + qb + 64 + c0) = ksl;
  }
  __syncthreads();
  // Coalesced transposed store: v_t[h][d][S]
#pragma unroll
  for (int i = 0; i < 2; ++i) {
    int cid = tid + i * 256;
    int d = cid >> 3, t8 = (cid & 7) * 8;
    size_t gb = ((size_t)(h * 64 + d)) * S_ + s0 + t8;
    *reinterpret_cast<ushort8*>(v_th + gb) = *reinterpret_cast<const ushort8*>(&VtH[d * 72 + t8]);
    *reinterpret_cast<ushort8*>(v_tl + gb) = *reinterpret_cast<const ushort8*>(&VtL[d * 72 + t8]);
  }
}

// ---------------------------------------------------------------------------
// Kernel B: folded retention v2.
//  - XCD-affinity block swizzle: flat id f -> xcd = f&7 owns heads
//    {2*(f&7), 2*(f&7)+1} (32 blocks/XCD, K/V working set 3 MiB < 4 MiB L2)
//    -> kills the 8x L3 refetch (FETCH 187 MB -> ~45 MB).
//  - XOR-swizzled LDS (T2): K rows 256 B, V rows 128 B, Sc rows 256 B, all
//    with byte ^= (row&7)<<4. Uniform bank spread on every access pattern
//    (stage writes, K/V frag reads, Sc writes, P reads) -> kills the 7 M
//    conflict cycles. LDS 123 -> 114 KiB.
//  - Q read directly as precomputed bf16 hi/lo (no per-pass f2bf).
// Structure (fold, double-buffer, reg-prefetch, 1 barrier/iter, factored
// decay, GroupNorm epilogue) unchanged from the proven v1.
// ---------------------------------------------------------------------------
#define KOFF(buf, row, cu) ((buf) * 16384 + (row) * 256 + ((((cu) * 2)) ^ (((row) & 7) << 4)))
#define VOFF(buf, d, tu)   ((buf) * 8192 + (d) * 128 + ((((tu) * 2)) ^ (((d) & 7) << 4)))
#define SCOFF(row, colb)   ((row) * 256 + ((colb) ^ (((row) & 7) << 4)))

__global__ __launch_bounds__(256) void retention_fold_kernel(
    const unsigned short* __restrict__ q_h, const unsigned short* __restrict__ q_l,
    const unsigned short* __restrict__ k_h, const unsigned short* __restrict__ k_l,
    const unsigned short* __restrict__ v_th, const unsigned short* __restrict__ v_tl,
    const float* __restrict__ gn_w, const float* __restrict__ gn_b,
    float* __restrict__ retn, int b) {
  __shared__ __align__(16) unsigned short Kh[2][64 * 128];  // 32 KiB swizzled
  __shared__ __align__(16) unsigned short Kl[2][64 * 128];  // 32 KiB
  __shared__ __align__(16) unsigned short Vh[2][64 * 64];   // 16 KiB [d][t]
  __shared__ __align__(16) unsigned short Vl[2][64 * 64];   // 16 KiB
  __shared__ __align__(16) float Sc[64 * 64];               // 16 KiB swizzled
  __shared__ float gnred[64][8];                            //  2 KiB

  char* KhB = (char*)Kh;
  char* KlB = (char*)Kl;
  char* VhB = (char*)Vh;
  char* VlB = (char*)Vl;
  char* ScB = (char*)Sc;

  int tid = threadIdx.x;
  int w = tid >> 6;
  int lane = tid & 63, ln = lane & 15, quad = lane >> 4;
  // XCD-affinity swizzle: dispatch round-robins flat id over 8 XCDs.
  int f = blockIdx.x;
  int h = ((f & 7) << 1) | ((f >> 7) & 1);
  int qp = (f >> 3) & 15;
  int prow = quad * 4;

  const float lo_c = -6.2383246250395075f, hi_c = -3.4657359027997265f;
  float gam = 1.f - __expf(lo_c + (hi_c - lo_c) * ((float)h * (1.f / 15.f)));
  float logg = __logf(gam);

  // Factored decay: gamma^(s-t) = gamma^(64*(qt-kt)) * gamma^lrow * gamma^-lcol
  float rowf[4], colf[4];
#pragma unroll
  for (int rr = 0; rr < 4; ++rr)
    rowf[rr] = __expf((float)(w * 16 + prow + rr) * logg);
#pragma unroll
  for (int ns = 0; ns < 4; ++ns)
    colf[ns] = __expf(-(float)(ns * 16 + ln) * logg);

  const unsigned short* khb = k_h + (size_t)h * S_ * 128;
  const unsigned short* klb = k_l + (size_t)h * S_ * 128;
  const unsigned short* vhb = v_th + (size_t)h * 64 * S_;
  const unsigned short* vlb = v_tl + (size_t)h * 64 * S_;

  for (int pass = 0; pass < 2; ++pass) {
    int qt = pass ? (31 - qp) : qp;
    int s0 = qt * 64;

    // Q fragments (A-layout), precomputed bf16 hi/lo.
    int sQ = s0 + w * 16 + ln;
    const unsigned short* qhp = q_h + ((size_t)h * S_ + sQ) * 128 + quad * 8;
    const unsigned short* qlp = q_l + ((size_t)h * S_ + sQ) * 128 + quad * 8;
    short8 qfh[4], qfl[4];
#pragma unroll
    for (int c = 0; c < 4; ++c) {
      qfh[c] = *reinterpret_cast<const short8*>(qhp + c * 32);
      qfl[c] = *reinterpret_cast<const short8*>(qlp + c * 32);
    }

    floatx4 accO[4];
#pragma unroll
    for (int i = 0; i < 4; ++i) accO[i] = (floatx4){0.f, 0.f, 0.f, 0.f};

    __syncthreads();  // prior pass's LDS reads complete before restaging
    // Prologue: stage tile kt=0 into buffer 0 (pure copies, swizzled dest).
#pragma unroll
    for (int i = 0; i < 4; ++i) {
      int cid = tid + i * 256;
      int r = cid >> 4, c8 = (cid & 15) * 8;
      int ko = KOFF(0, r, c8);
      *reinterpret_cast<ushort8*>(KhB + ko) =
          *reinterpret_cast<const ushort8*>(khb + (size_t)r * 128 + c8);
      *reinterpret_cast<ushort8*>(KlB + ko) =
          *reinterpret_cast<const ushort8*>(klb + (size_t)r * 128 + c8);
    }
#pragma unroll
    for (int i = 0; i < 2; ++i) {
      int cid = tid + i * 256;
      int d = cid >> 3, t8 = (cid & 7) * 8;
      int vo = VOFF(0, d, t8);
      *reinterpret_cast<ushort8*>(VhB + vo) =
          *reinterpret_cast<const ushort8*>(vhb + (size_t)d * S_ + t8);
      *reinterpret_cast<ushort8*>(VlB + vo) =
          *reinterpret_cast<const ushort8*>(vlb + (size_t)d * S_ + t8);
    }

    for (int kt = 0; kt <= qt; ++kt) {
      int cur = kt & 1;
      __syncthreads();  // buf[cur] staged; prior iter's reads of buf[cur^1] done

      // Prefetch next K/V tile into registers (global loads overlap QK below).
      ushort8 skh[4], skl[4], svh[2], svl[2];
      if (kt < qt) {
        int t0n = (kt + 1) * 64;
#pragma unroll
        for (int i = 0; i < 4; ++i) {
          int cid = tid + i * 256;
          int r = cid >> 4, c8 = (cid & 15) * 8;
          skh[i] = *reinterpret_cast<const ushort8*>(khb + ((size_t)(t0n + r)) * 128 + c8);
          skl[i] = *reinterpret_cast<const ushort8*>(klb + ((size_t)(t0n + r)) * 128 + c8);
        }
#pragma unroll
        for (int i = 0; i < 2; ++i) {
          int cid = tid + i * 256;
          int d = cid >> 3, t8 = (cid & 7) * 8;
          svh[i] = *reinterpret_cast<const ushort8*>(vhb + (size_t)d * S_ + t0n + t8);
          svl[i] = *reinterpret_cast<const ushort8*>(vlb + (size_t)d * S_ + t0n + t8);
        }
      }

      // QK^T split-MFMA (proven structure, swizzled K reads)
      floatx4 accS[4];
#pragma unroll
      for (int ns = 0; ns < 4; ++ns) {
        floatx4 a = (floatx4){0.f, 0.f, 0.f, 0.f};
        int row = ns * 16 + ln;
#pragma unroll
        for (int ks = 0; ks < 4; ++ks) {
          int off = cur * 16384 + row * 256 + ((ks * 64 + quad * 16) ^ ((ln & 7) << 4));
          short8 kh = *reinterpret_cast<const short8*>(KhB + off);
          short8 kl = *reinterpret_cast<const short8*>(KlB + off);
          a = __builtin_amdgcn_mfma_f32_16x16x32_bf16(qfh[ks], kh, a, 0, 0, 0);
          a = __builtin_amdgcn_mfma_f32_16x16x32_bf16(qfl[ks], kh, a, 0, 0, 0);
          a = __builtin_amdgcn_mfma_f32_16x16x32_bf16(qfh[ks], kl, a, 0, 0, 0);
        }
        accS[ns] = a;
      }

      // Factored decay (+ causal select only on the diagonal tile) -> Sc.
      float tf = __expf((float)(64 * (qt - kt)) * logg);
      float trf[4];
#pragma unroll
      for (int rr = 0; rr < 4; ++rr) trf[rr] = tf * rowf[rr];
      if (kt < qt) {
#pragma unroll
        for (int ns = 0; ns < 4; ++ns) {
          int col = ns * 16 + ln;
#pragma unroll
          for (int rr = 0; rr < 4; ++rr) {
            int row = w * 16 + prow + rr;
            *reinterpret_cast<float*>(ScB + SCOFF(row, col * 4)) =
                accS[ns][rr] * trf[rr] * colf[ns];
          }
        }
      } else {
#pragma unroll
        for (int ns = 0; ns < 4; ++ns) {
          int col = ns * 16 + ln;
#pragma unroll
          for (int rr = 0; rr < 4; ++rr) {
            int row = w * 16 + prow + rr;
            float v = accS[ns][rr] * trf[rr] * colf[ns];
            *reinterpret_cast<float*>(ScB + SCOFF(row, col * 4)) =
                (row >= col) ? v : 0.f;
          }
        }
      }

      // Write prefetched tile into the alternate buffer (vmcnt drains here).
      if (kt < qt) {
        int nx = cur ^ 1;
#pragma unroll
        for (int i = 0; i < 4; ++i) {
          int cid = tid + i * 256;
          int r = cid >> 4, c8 = (cid & 15) * 8;
          int ko = KOFF(nx, r, c8);
          *reinterpret_cast<ushort8*>(KhB + ko) = skh[i];
          *reinterpret_cast<ushort8*>(KlB + ko) = skl[i];
        }
#pragma unroll
        for (int i = 0; i < 2; ++i) {
          int cid = tid + i * 256;
          int d = cid >> 3, t8 = (cid & 7) * 8;
          int vo = VOFF(nx, d, t8);
          *reinterpret_cast<ushort8*>(VhB + vo) = svh[i];
          *reinterpret_cast<ushort8*>(VlB + vo) = svl[i];
        }
      }

      // PV split-MFMA. Sc rows read here are written by THIS wave only.
#pragma unroll
      for (int ks = 0; ks < 2; ++ks) {
        int prw = w * 16 + ln;
        int cb = ks * 128 + quad * 32;
        float4v p0 = *reinterpret_cast<const float4v*>(ScB + SCOFF(prw, cb));
        float4v p1 = *reinterpret_cast<const float4v*>(ScB + SCOFF(prw, cb + 16));
        short8 ph, pl;
#pragma unroll
        for (int j = 0; j < 4; ++j) {
          unsigned short hh = f2bf(p0[j]);
          ph[j] = (short)hh;
          pl[j] = (short)f2bf(p0[j] - bf2f(hh));
          unsigned short hh2 = f2bf(p1[j]);
          ph[4 + j] = (short)hh2;
          pl[4 + j] = (short)f2bf(p1[j] - bf2f(hh2));
        }
#pragma unroll
        for (int ds = 0; ds < 4; ++ds) {
          int d = ds * 16 + ln;
          int voff = cur * 8192 + d * 128 + ((ks * 64 + quad * 16) ^ ((ln & 7) << 4));
          short8 vh = *reinterpret_cast<const short8*>(VhB + voff);
          short8 vl = *reinterpret_cast<const short8*>(VlB + voff);
          accO[ds] = __builtin_amdgcn_mfma_f32_16x16x32_bf16(ph, vh, accO[ds], 0, 0, 0);
          accO[ds] = __builtin_amdgcn_mfma_f32_16x16x32_bf16(pl, vh, accO[ds], 0, 0, 0);
          accO[ds] = __builtin_amdgcn_mfma_f32_16x16x32_bf16(ph, vl, accO[ds], 0, 0, 0);
        }
      }
    }

    // Epilogue: accO -> Sc as Out[row][d], then the proven (r2,sub) GroupNorm.
    // All LDS traffic here is wave-private (rows w*16..w*16+15), barrier-free.
#pragma unroll
    for (int ds = 0; ds < 4; ++ds) {
#pragma unroll
      for (int rr = 0; rr < 4; ++rr) {
        int row = w * 16 + quad * 4 + rr;
        *reinterpret_cast<float*>(ScB + SCOFF(row, (ds * 16 + ln) * 4)) = accO[ds][rr];
      }
    }

    int r2 = tid >> 2;
    int sub = tid & 3;
    float a16[16];
#pragma unroll
    for (int c = 0; c < 4; ++c) {
      float4v t = *reinterpret_cast<const float4v*>(ScB + SCOFF(r2, sub * 64 + c * 16));
#pragma unroll
      for (int j = 0; j < 4; ++j) a16[c * 4 + j] = t[j];
    }

    float psum = 0.f, psq = 0.f;
#pragma unroll
    for (int i = 0; i < 16; ++i) { psum += a16[i]; psq += a16[i] * a16[i]; }
    gnred[r2][sub] = psum;
    gnred[r2][4 + sub] = psq;
    float sum = gnred[r2][0] + gnred[r2][1] + gnred[r2][2] + gnred[r2][3];
    float sq = gnred[r2][4] + gnred[r2][5] + gnred[r2][6] + gnred[r2][7];
    float mean = sum * (1.f / 64.f);
    float var = sq * (1.f / 64.f) - mean * mean;
    float rstd = rsqrtf(var + 1e-5f);

    size_t obase = ((size_t)(b * S_ + s0 + r2)) * HID_ + h * DH_ + sub * 16;
#pragma unroll
    for (int i = 0; i < 16; ++i) {
      float gw = gn_w[h * DH_ + sub * 16 + i];
      float gb = gn_b[h * DH_ + sub * 16 + i];
      retn[obase + i] = (a16[i] - mean) * rstd * gw + gb;
    }
  }
}

// ---------------------------------------------------------------------------
// GEMM 1 (gate): unchanged, proven.
// ---------------------------------------------------------------------------
__global__ __launch_bounds__(256) void gemm_gate_kernel(
    const unsigned short* __restrict__ A, const unsigned short* __restrict__ Bt,
    const float* __restrict__ retn, unsigned short* __restrict__ pre_hi,
    unsigned short* __restrict__ pre_lo) {
  const int K = HID_;
  __shared__ __align__(16) unsigned short Al[128 * 56];
  __shared__ __align__(16) unsigned short Bl[128 * 56];

  int tid = threadIdx.x;
  int lane = tid & 63, ln = lane & 15, quad = lane >> 4;
  int w = tid >> 6, wm = w >> 1, wn = w & 1;
  int m0 = blockIdx.y * 128, n0 = blockIdx.x * 128;

  floatx4 acc[4][4];
#pragma unroll
  for (int i = 0; i < 4; ++i)
#pragma unroll
    for (int j = 0; j < 4; ++j) acc[i][j] = (floatx4){0.f, 0.f, 0.f, 0.f};

  for (int k0 = 0; k0 < K; k0 += 32) {
    __syncthreads();
#pragma unroll
    for (int i = 0; i < 2; ++i) {
      int cid = tid + i * 256;
      int r = cid >> 2, c8 = (cid & 3) * 8;
      *reinterpret_cast<ushort8*>(&Al[r * 56 + c8]) =
          *reinterpret_cast<const ushort8*>(A + (size_t)(m0 + r) * K + k0 + c8);
      *reinterpret_cast<ushort8*>(&Bl[r * 56 + c8]) =
          *reinterpret_cast<const ushort8*>(Bt + (size_t)(n0 + r) * K + k0 + c8);
    }
    __syncthreads();

    short8 af[4], bfr[4];
#pragma unroll
    for (int i = 0; i < 4; ++i) {
      af[i] = *reinterpret_cast<const short8*>(&Al[(wm * 64 + i * 16 + ln) * 56 + quad * 8]);
      bfr[i] = *reinterpret_cast<const short8*>(&Bl[(wn * 64 + i * 16 + ln) * 56 + quad * 8]);
    }
#pragma unroll
    for (int mi = 0; mi < 4; ++mi)
#pragma unroll
      for (int ni = 0; ni < 4; ++ni)
        acc[mi][ni] = __builtin_amdgcn_mfma_f32_16x16x32_bf16(af[mi], bfr[ni], acc[mi][ni], 0, 0, 0);
  }

#pragma unroll
  for (int mi = 0; mi < 4; ++mi) {
#pragma unroll
    for (int r = 0; r < 4; ++r) {
      int row = m0 + wm * 64 + mi * 16 + quad * 4 + r;
#pragma unroll
      for (int ni = 0; ni < 4; ++ni) {
        int col = n0 + wn * 64 + ni * 16 + ln;
        float g = acc[mi][ni][r];
        float val = g * (1.f / (1.f + __expf(-g))) + retn[(size_t)row * HID_ + col];
        unsigned short hh = f2bf(val);
        size_t oidx = (size_t)row * HID_ + col;
        pre_hi[oidx] = hh;
        pre_lo[oidx] = f2bf(val - bf2f(hh));
      }
    }
  }
}

// ---------------------------------------------------------------------------
// GEMM 2 (output): unchanged, proven.
// ---------------------------------------------------------------------------
__global__ __launch_bounds__(256) void gemm_out_kernel(
    const unsigned short* __restrict__ Ah, const unsigned short* __restrict__ Alo,
    const unsigned short* __restrict__ Bth, const unsigned short* __restrict__ Btlo,
    float* __restrict__ out_f) {
  const int K = HID_;
  __shared__ __align__(16) unsigned short AhS[128 * 56];
  __shared__ __align__(16) unsigned short AlS[128 * 56];
  __shared__ __align__(16) unsigned short BhS[128 * 56];
  __shared__ __align__(16) unsigned short BlS[128 * 56];

  int tid = threadIdx.x;
  int lane = tid & 63, ln = lane & 15, quad = lane >> 4;
  int w = tid >> 6, wm = w >> 1, wn = w & 1;
  int m0 = blockIdx.y * 128, n0 = blockIdx.x * 128;

  floatx4 acc[4][4];
#pragma unroll
  for (int i = 0; i < 4; ++i)
#pragma unroll
    for (int j = 0; j < 4; ++j) acc[i][j] = (floatx4){0.f, 0.f, 0.f, 0.f};

  for (int k0 = 0; k0 < K; k0 += 32) {
    __syncthreads();
#pragma unroll
    for (int i = 0; i < 2; ++i) {
      int cid = tid + i * 256;
      int r = cid >> 2, c8 = (cid & 3) * 8;
      size_t ga = (size_t)(m0 + r) * K + k0 + c8;
      size_t gb = (size_t)(n0 + r) * K + k0 + c8;
      *reinterpret_cast<ushort8*>(&AhS[r * 56 + c8]) = *reinterpret_cast<const ushort8*>(Ah + ga);
      *reinterpret_cast<ushort8*>(&AlS[r * 56 + c8]) = *reinterpret_cast<const ushort8*>(Alo + ga);
      *reinterpret_cast<ushort8*>(&BhS[r * 56 + c8]) = *reinterpret_cast<const ushort8*>(Bth + gb);
      *reinterpret_cast<ushort8*>(&BlS[r * 56 + c8]) = *reinterpret_cast<const ushort8*>(Btlo + gb);
    }
    __syncthreads();

    short8 afh[4], afl[4], bfh[4], bfl[4];
#pragma unroll
    for (int i = 0; i < 4; ++i) {
      int ao = (wm * 64 + i * 16 + ln) * 56 + quad * 8;
      int bo = (wn * 64 + i * 16 + ln) * 56 + quad * 8;
      afh[i] = *reinterpret_cast<const short8*>(&AhS[ao]);
      afl[i] = *reinterpret_cast<const short8*>(&AlS[ao]);
      bfh[i] = *reinterpret_cast<const short8*>(&BhS[bo]);
      bfl[i] = *reinterpret_cast<const short8*>(&BlS[bo]);
    }
#pragma unroll
    for (int mi = 0; mi < 4; ++mi)
#pragma unroll
      for (int ni = 0; ni < 4; ++ni) {
        floatx4 a = acc[mi][ni];
        a = __builtin_amdgcn_mfma_f32_16x16x32_bf16(afh[mi], bfh[ni], a, 0, 0, 0);
        a = __builtin_amdgcn_mfma_f32_16x16x32_bf16(afl[mi], bfh[ni], a, 0, 0, 0);
        a = __builtin_amdgcn_mfma_f32_16x16x32_bf16(afh[mi], bfl[ni], a, 0, 0, 0);
        acc[mi][ni] = a;
      }
  }

#pragma unroll
  for (int mi = 0; mi < 4; ++mi) {
#pragma unroll
    for (int r = 0; r < 4; ++r) {
      int row = m0 + wm * 64 + mi * 16 + quad * 4 + r;
#pragma unroll
      for (int ni = 0; ni < 4; ++ni) {
        int col = n0 + wn * 64 + ni * 16 + ln;
        out_f[(size_t)row * HID_ + col] = acc[mi][ni][r];
      }
    }
  }
}

// ---------------------------------------------------------------------------
extern "C" void kernel_launch(void* const* d_in, const int* in_sizes, int n_in,
                              void* d_out, int out_size, void* d_ws,
                              size_t ws_size, hipStream_t stream) {
  (void)in_sizes; (void)n_in; (void)out_size; (void)ws_size;
  const float* x = (const float*)d_in[0];
  const float* wq = (const float*)d_in[1];
  const float* bq = (const float*)d_in[2];
  const float* wk = (const float*)d_in[3];
  const float* bk = (const float*)d_in[4];
  const float* wv = (const float*)d_in[5];
  const float* theta = (const float*)d_in[6];
  const float* gn_w = (const float*)d_in[7];
  const float* gn_b = (const float*)d_in[8];
  const float* w1 = (const float*)d_in[9];
  const float* w2 = (const float*)d_in[10];

  const size_t MB = 1024 * 1024;
  char* ws = (char*)d_ws;
  unsigned short* x_bf   = (unsigned short*)(ws + 0 * MB);    //  8 MiB
  unsigned short* w1t    = (unsigned short*)(ws + 8 * MB);    //  2 MiB
  unsigned short* w2t_hi = (unsigned short*)(ws + 10 * MB);   //  2 MiB
  unsigned short* w2t_lo = (unsigned short*)(ws + 12 * MB);   //  2 MiB
  unsigned short* q_h    = (unsigned short*)(ws + 14 * MB);   //  8 MiB (1 batch)
  unsigned short* q_l    = (unsigned short*)(ws + 22 * MB);   //  8 MiB
  unsigned short* k_h    = (unsigned short*)(ws + 30 * MB);   //  8 MiB
  unsigned short* k_l    = (unsigned short*)(ws + 38 * MB);   //  8 MiB
  unsigned short* v_th   = (unsigned short*)(ws + 46 * MB);   //  4 MiB
  unsigned short* v_tl   = (unsigned short*)(ws + 50 * MB);   //  4 MiB
  float*          retn   = (float*)(ws + 54 * MB);            // 16 MiB (both batches)
  unsigned short* pre_hi = (unsigned short*)(ws + 14 * MB);   //  8 MiB (alias q_h, dead by then)
  unsigned short* pre_lo = (unsigned short*)(ws + 22 * MB);   //  8 MiB (alias q_l)
  float* out = (float*)d_out;

  convert_kernel<<<dim3(24576), 256, 0, stream>>>(x, w1, w2, x_bf, w1t, w2t_hi, w2t_lo);
  for (int b = 0; b < B_; ++b) {
    qkv_kernel<<<dim3(S_ / 64, H_), 256, 0, stream>>>(
        x, wq, bq, wk, bk, wv, theta, q_h, q_l, k_h, k_l, v_th, v_tl, b);
    retention_fold_kernel<<<dim3(256), 256, 0, stream>>>(
        q_h, q_l, k_h, k_l, v_th, v_tl, gn_w, gn_b, retn, b);
  }
  gemm_gate_kernel<<<dim3(HID_ / 128, (B_ * S_) / 128), 256, 0, stream>>>(
      x_bf, w1t, retn, pre_hi, pre_lo);
  gemm_out_kernel<<<dim3(HID_ / 128, (B_ * S_) / 128), 256, 0, stream>>>(
      pre_hi, pre_lo, w2t_hi, w2t_lo, out);
}

// Round 5
// 378.193 us; speedup vs baseline: 1.0516x; 1.0516x over previous
//
#include <hip/hip_runtime.h>
#include <cstdint>
#include <cstddef>

#define B_ 2
#define S_ 2048
#define HID_ 1024
#define H_ 16
#define DH_ 64

typedef __attribute__((ext_vector_type(8))) short short8;
typedef __attribute__((ext_vector_type(8))) unsigned short ushort8;
typedef __attribute__((ext_vector_type(4))) unsigned short ushort4v;
typedef __attribute__((ext_vector_type(4))) float floatx4;
typedef __attribute__((ext_vector_type(4))) float float4v;

static __device__ __forceinline__ unsigned short f2bf(float f) {
  unsigned int u = __float_as_uint(f);
  u += 0x7fffu + ((u >> 16) & 1u);
  return (unsigned short)(u >> 16);
}
static __device__ __forceinline__ float bf2f(unsigned short h) {
  return __uint_as_float(((unsigned int)h) << 16);
}

// ---------------------------------------------------------------------------
// Kernel 0: conversions. (unchanged, proven)
// ---------------------------------------------------------------------------
__global__ __launch_bounds__(256) void convert_kernel(
    const float* __restrict__ x, const float* __restrict__ w1,
    const float* __restrict__ w2, unsigned short* __restrict__ x_bf,
    unsigned short* __restrict__ w1t, unsigned short* __restrict__ w2t_hi,
    unsigned short* __restrict__ w2t_lo) {
  const int NX = B_ * S_ * HID_;
  const int NW = HID_ * HID_;
  int idx = blockIdx.x * 256 + threadIdx.x;
  if (idx < NX) {
    x_bf[idx] = f2bf(x[idx]);
  } else if (idx < NX + NW) {
    int i = idx - NX;
    int n = i >> 10, k = i & 1023;
    w1t[i] = f2bf(w1[k * HID_ + n]);
  } else if (idx < NX + 2 * NW) {
    int i = idx - NX - NW;
    int n = i >> 10, k = i & 1023;
    float v = w2[k * HID_ + n];
    unsigned short h = f2bf(v);
    w2t_hi[i] = h;
    w2t_lo[i] = f2bf(v - bf2f(h));
  }
}

// ---------------------------------------------------------------------------
// Kernel A: per-head QKV projection + bias + rotary. Emits split-bf16 for
// Q AND K (rotated, [h][s][128]) and transposed split-bf16 V ([h][d][S]).
// (unchanged, proven)
// ---------------------------------------------------------------------------
__global__ __launch_bounds__(256) void qkv_kernel(
    const float* __restrict__ x, const float* __restrict__ wq,
    const float* __restrict__ bq, const float* __restrict__ wk,
    const float* __restrict__ bk, const float* __restrict__ wv,
    const float* __restrict__ theta,
    unsigned short* __restrict__ q_h, unsigned short* __restrict__ q_l,
    unsigned short* __restrict__ k_h, unsigned short* __restrict__ k_l,
    unsigned short* __restrict__ v_th, unsigned short* __restrict__ v_tl,
    int b) {
  __shared__ __align__(16) float xs[64 * 68];
  __shared__ __align__(16) float wqs[64 * 68];
  __shared__ __align__(16) float wks[64 * 68];
  __shared__ __align__(16) float wvs[64 * 68];

  int tid = threadIdx.x;
  int st = blockIdx.x, h = blockIdx.y;
  int s0 = st * 64;

#pragma unroll
  for (int i = 0; i < 4; ++i) {
    int cid = tid + i * 256;
    int r = cid >> 4, c4 = (cid & 15) * 4;
    *reinterpret_cast<float4v*>(&xs[r * 68 + c4]) =
        *reinterpret_cast<const float4v*>(x + ((size_t)(b * S_ + s0 + r)) * HID_ + h * DH_ + c4);
  }
#pragma unroll
  for (int i = 0; i < 4; ++i) {
    int cid = tid + i * 256;
    int d = cid >> 4, c4 = (cid & 15) * 4;
    *reinterpret_cast<float4v*>(&wqs[d * 68 + c4]) =
        *reinterpret_cast<const float4v*>(wq + (size_t)(h * DH_ + d) * DH_ + c4);
    *reinterpret_cast<float4v*>(&wks[d * 68 + c4]) =
        *reinterpret_cast<const float4v*>(wk + (size_t)(h * DH_ + d) * DH_ + c4);
    *reinterpret_cast<float4v*>(&wvs[d * 68 + c4]) =
        *reinterpret_cast<const float4v*>(wv + (size_t)(h * DH_ + d) * DH_ + c4);
  }
  __syncthreads();

  int rg = tid >> 3;
  int cg = tid & 7;
  int r0 = rg * 2, c0 = cg * 8;

  float aq[2][8], ak[2][8], av[2][8];
#pragma unroll
  for (int i = 0; i < 2; ++i)
#pragma unroll
    for (int j = 0; j < 8; ++j) { aq[i][j] = 0.f; ak[i][j] = 0.f; av[i][j] = 0.f; }

  for (int d = 0; d < 64; ++d) {
    float x0 = xs[(r0 + 0) * 68 + d];
    float x1 = xs[(r0 + 1) * 68 + d];
#pragma unroll
    for (int j = 0; j < 8; ++j) {
      float wqv = wqs[d * 68 + c0 + j];
      float wkv = wks[d * 68 + c0 + j];
      float wvv = wvs[d * 68 + c0 + j];
      aq[0][j] += x0 * wqv; aq[1][j] += x1 * wqv;
      ak[0][j] += x0 * wkv; ak[1][j] += x1 * wkv;
      av[0][j] += x0 * wvv; av[1][j] += x1 * wvv;
    }
  }

  float thv[8], bqv[8], bkv[8];
#pragma unroll
  for (int j = 0; j < 8; ++j) {
    thv[j] = theta[h * DH_ + c0 + j];
    bqv[j] = bq[h * DH_ + c0 + j];
    bkv[j] = bk[h * DH_ + c0 + j];
  }

  // Reuse xs/wqs LDS as bf16 V-transpose staging (all reads of them are done).
  __syncthreads();
  unsigned short* VtH = reinterpret_cast<unsigned short*>(xs);   // [64 d][72]
  unsigned short* VtL = reinterpret_cast<unsigned short*>(wqs);  // [64 d][72]

#pragma unroll
  for (int i = 0; i < 2; ++i) {
    int s = s0 + r0 + i;
    size_t qb = ((size_t)h * S_ + s) * 128;
    ushort8 qch, qcl, qsh, qsl, kch, kcl, ksh, ksl;
#pragma unroll
    for (int j = 0; j < 8; ++j) {
      float q = aq[i][j] + bqv[j];
      float k = ak[i][j] + bkv[j];
      float ang = (float)s * thv[j];
      float cs = cosf(ang), sn = sinf(ang);
      float qc = q * cs, qs = q * sn;
      unsigned short hq1 = f2bf(qc);
      qch[j] = hq1;
      qcl[j] = f2bf(qc - bf2f(hq1));
      unsigned short hq2 = f2bf(qs);
      qsh[j] = hq2;
      qsl[j] = f2bf(qs - bf2f(hq2));
      float kc = k * cs, ksn = k * sn;
      unsigned short h1 = f2bf(kc);
      kch[j] = h1;
      kcl[j] = f2bf(kc - bf2f(h1));
      unsigned short h2 = f2bf(ksn);
      ksh[j] = h2;
      ksl[j] = f2bf(ksn - bf2f(h2));
      float vv = av[i][j];
      unsigned short vh1 = f2bf(vv);
      VtH[(c0 + j) * 72 + (r0 + i)] = vh1;
      VtL[(c0 + j) * 72 + (r0 + i)] = f2bf(vv - bf2f(vh1));
    }
    *reinterpret_cast<ushort8*>(q_h + qb + c0) = qch;
    *reinterpret_cast<ushort8*>(q_h + qb + 64 + c0) = qsh;
    *reinterpret_cast<ushort8*>(q_l + qb + c0) = qcl;
    *reinterpret_cast<ushort8*>(q_l + qb + 64 + c0) = qsl;
    *reinterpret_cast<ushort8*>(k_h + qb + c0) = kch;
    *reinterpret_cast<ushort8*>(k_h + qb + 64 + c0) = ksh;
    *reinterpret_cast<ushort8*>(k_l + qb + c0) = kcl;
    *reinterpret_cast<ushort8*>(k_l + qb + 64 + c0) = ksl;
  }
  __syncthreads();
  // Coalesced transposed store: v_t[h][d][S]
#pragma unroll
  for (int i = 0; i < 2; ++i) {
    int cid = tid + i * 256;
    int d = cid >> 3, t8 = (cid & 7) * 8;
    size_t gb = ((size_t)(h * 64 + d)) * S_ + s0 + t8;
    *reinterpret_cast<ushort8*>(v_th + gb) = *reinterpret_cast<const ushort8*>(&VtH[d * 72 + t8]);
    *reinterpret_cast<ushort8*>(v_tl + gb) = *reinterpret_cast<const ushort8*>(&VtL[d * 72 + t8]);
  }
}

// ---------------------------------------------------------------------------
// Kernel B: retention v3 — occupancy restructure (the r4 lesson: 114 KiB LDS
// forced 1 wave/SIMD; all stalls serialized).
//  - One q-tile per block, grid 512/batch. Decode: same head for f and f+256
//    (f&256 selects qt = qp vs 31-qp) -> the round-robin dispatch (validated
//    by r4's exact FETCH drop) co-schedules f,f+256 on one CU: 33 iters/CU,
//    one head's K/V stream per CU, heads {2x,2x+1} per XCD (L2-fit kept).
//  - Single-buffered K/V (LDS 66 KiB < 80) -> 2 blocks/CU = 2 waves/SIMD.
//    Register prefetch issued one full compute phase ahead; the co-resident
//    block hides barrier/vmcnt drains (the thing 1 wave/SIMD could not).
//  - XOR-swizzled LDS, factored decay, GroupNorm epilogue: unchanged/proven.
// Numerics bit-identical to r4 (same values, same accumulation order).
// ---------------------------------------------------------------------------
#define SCOFF(row, colb)   ((row) * 256 + ((colb) ^ (((row) & 7) << 4)))

__global__ __launch_bounds__(256, 2) void retention_fold_kernel(
    const unsigned short* __restrict__ q_h, const unsigned short* __restrict__ q_l,
    const unsigned short* __restrict__ k_h, const unsigned short* __restrict__ k_l,
    const unsigned short* __restrict__ v_th, const unsigned short* __restrict__ v_tl,
    const float* __restrict__ gn_w, const float* __restrict__ gn_b,
    float* __restrict__ retn, int b) {
  __shared__ __align__(16) unsigned short Kh[64 * 128];  // 16 KiB swizzled
  __shared__ __align__(16) unsigned short Kl[64 * 128];  // 16 KiB
  __shared__ __align__(16) unsigned short Vh[64 * 64];   //  8 KiB [d][t]
  __shared__ __align__(16) unsigned short Vl[64 * 64];   //  8 KiB
  __shared__ __align__(16) float Sc[64 * 64];            // 16 KiB swizzled
  __shared__ float gnred[64][8];                         //  2 KiB

  char* KhB = (char*)Kh;
  char* KlB = (char*)Kl;
  char* VhB = (char*)Vh;
  char* VlB = (char*)Vl;
  char* ScB = (char*)Sc;

  int tid = threadIdx.x;
  int w = tid >> 6;
  int lane = tid & 63, ln = lane & 15, quad = lane >> 4;
  // Decode: xcd = f&7, qp = (f>>3)&15, hb = (f>>7)&1, half = (f>>8)&1.
  // f and f+256 share (xcd, qp, hb) -> same head, complementary q-tiles.
  int f = blockIdx.x;
  int h = ((f & 7) << 1) | ((f >> 7) & 1);
  int qp = (f >> 3) & 15;
  int qt = (f & 256) ? (31 - qp) : qp;
  int s0 = qt * 64;
  int prow = quad * 4;

  const float lo_c = -6.2383246250395075f, hi_c = -3.4657359027997265f;
  float gam = 1.f - __expf(lo_c + (hi_c - lo_c) * ((float)h * (1.f / 15.f)));
  float logg = __logf(gam);

  // Factored decay: gamma^(s-t) = gamma^(64*(qt-kt)) * gamma^lrow * gamma^-lcol
  float rowf[4], colf[4];
#pragma unroll
  for (int rr = 0; rr < 4; ++rr)
    rowf[rr] = __expf((float)(w * 16 + prow + rr) * logg);
#pragma unroll
  for (int ns = 0; ns < 4; ++ns)
    colf[ns] = __expf(-(float)(ns * 16 + ln) * logg);

  const unsigned short* khb = k_h + (size_t)h * S_ * 128;
  const unsigned short* klb = k_l + (size_t)h * S_ * 128;
  const unsigned short* vhb = v_th + (size_t)h * 64 * S_;
  const unsigned short* vlb = v_tl + (size_t)h * 64 * S_;

  // Q fragments (A-layout), precomputed bf16 hi/lo.
  int sQ = s0 + w * 16 + ln;
  const unsigned short* qhp = q_h + ((size_t)h * S_ + sQ) * 128 + quad * 8;
  const unsigned short* qlp = q_l + ((size_t)h * S_ + sQ) * 128 + quad * 8;
  short8 qfh[4], qfl[4];
#pragma unroll
  for (int c = 0; c < 4; ++c) {
    qfh[c] = *reinterpret_cast<const short8*>(qhp + c * 32);
    qfl[c] = *reinterpret_cast<const short8*>(qlp + c * 32);
  }

  floatx4 accO[4];
#pragma unroll
  for (int i = 0; i < 4; ++i) accO[i] = (floatx4){0.f, 0.f, 0.f, 0.f};

  // Prologue: load tile 0 -> regs -> LDS; prefetch tile 1 into regs.
  ushort8 skh[4], skl[4], svh[2], svl[2];
#pragma unroll
  for (int i = 0; i < 4; ++i) {
    int cid = tid + i * 256;
    int r = cid >> 4, c8 = (cid & 15) * 8;
    skh[i] = *reinterpret_cast<const ushort8*>(khb + (size_t)r * 128 + c8);
    skl[i] = *reinterpret_cast<const ushort8*>(klb + (size_t)r * 128 + c8);
  }
#pragma unroll
  for (int i = 0; i < 2; ++i) {
    int cid = tid + i * 256;
    int d = cid >> 3, t8 = (cid & 7) * 8;
    svh[i] = *reinterpret_cast<const ushort8*>(vhb + (size_t)d * S_ + t8);
    svl[i] = *reinterpret_cast<const ushort8*>(vlb + (size_t)d * S_ + t8);
  }
#pragma unroll
  for (int i = 0; i < 4; ++i) {
    int cid = tid + i * 256;
    int r = cid >> 4, c8 = (cid & 15) * 8;
    int ko = r * 256 + (((cid & 15) * 16) ^ ((r & 7) << 4));
    *reinterpret_cast<ushort8*>(KhB + ko) = skh[i];
    *reinterpret_cast<ushort8*>(KlB + ko) = skl[i];
  }
#pragma unroll
  for (int i = 0; i < 2; ++i) {
    int cid = tid + i * 256;
    int d = cid >> 3, t8 = (cid & 7) * 8;
    int vo = d * 128 + (((cid & 7) * 16) ^ ((d & 7) << 4));
    *reinterpret_cast<ushort8*>(VhB + vo) = svh[i];
    *reinterpret_cast<ushort8*>(VlB + vo) = svl[i];
  }
  if (qt >= 1) {
#pragma unroll
    for (int i = 0; i < 4; ++i) {
      int cid = tid + i * 256;
      int r = cid >> 4, c8 = (cid & 15) * 8;
      skh[i] = *reinterpret_cast<const ushort8*>(khb + ((size_t)(64 + r)) * 128 + c8);
      skl[i] = *reinterpret_cast<const ushort8*>(klb + ((size_t)(64 + r)) * 128 + c8);
    }
#pragma unroll
    for (int i = 0; i < 2; ++i) {
      int cid = tid + i * 256;
      int d = cid >> 3, t8 = (cid & 7) * 8;
      svh[i] = *reinterpret_cast<const ushort8*>(vhb + (size_t)d * S_ + 64 + t8);
      svl[i] = *reinterpret_cast<const ushort8*>(vlb + (size_t)d * S_ + 64 + t8);
    }
  }
  __syncthreads();

  for (int kt = 0; kt <= qt; ++kt) {
    // QK^T split-MFMA (proven structure, swizzled K reads)
    floatx4 accS[4];
#pragma unroll
    for (int ns = 0; ns < 4; ++ns) {
      floatx4 a = (floatx4){0.f, 0.f, 0.f, 0.f};
      int row = ns * 16 + ln;
#pragma unroll
      for (int ks = 0; ks < 4; ++ks) {
        int off = row * 256 + ((ks * 64 + quad * 16) ^ ((ln & 7) << 4));
        short8 kh = *reinterpret_cast<const short8*>(KhB + off);
        short8 kl = *reinterpret_cast<const short8*>(KlB + off);
        a = __builtin_amdgcn_mfma_f32_16x16x32_bf16(qfh[ks], kh, a, 0, 0, 0);
        a = __builtin_amdgcn_mfma_f32_16x16x32_bf16(qfl[ks], kh, a, 0, 0, 0);
        a = __builtin_amdgcn_mfma_f32_16x16x32_bf16(qfh[ks], kl, a, 0, 0, 0);
      }
      accS[ns] = a;
    }

    // Factored decay (+ causal select only on the diagonal tile) -> Sc.
    float tf = __expf((float)(64 * (qt - kt)) * logg);
    float trf[4];
#pragma unroll
    for (int rr = 0; rr < 4; ++rr) trf[rr] = tf * rowf[rr];
    if (kt < qt) {
#pragma unroll
      for (int ns = 0; ns < 4; ++ns) {
        int col = ns * 16 + ln;
#pragma unroll
        for (int rr = 0; rr < 4; ++rr) {
          int row = w * 16 + prow + rr;
          *reinterpret_cast<float*>(ScB + SCOFF(row, col * 4)) =
              accS[ns][rr] * trf[rr] * colf[ns];
        }
      }
    } else {
#pragma unroll
      for (int ns = 0; ns < 4; ++ns) {
        int col = ns * 16 + ln;
#pragma unroll
        for (int rr = 0; rr < 4; ++rr) {
          int row = w * 16 + prow + rr;
          float v = accS[ns][rr] * trf[rr] * colf[ns];
          *reinterpret_cast<float*>(ScB + SCOFF(row, col * 4)) =
              (row >= col) ? v : 0.f;
        }
      }
    }

    // PV split-MFMA. Sc rows read here are written by THIS wave only
    // (in-order DS within a wave; no barrier needed).
#pragma unroll
    for (int ks = 0; ks < 2; ++ks) {
      int prw = w * 16 + ln;
      int cb = ks * 128 + quad * 32;
      float4v p0 = *reinterpret_cast<const float4v*>(ScB + SCOFF(prw, cb));
      float4v p1 = *reinterpret_cast<const float4v*>(ScB + SCOFF(prw, cb + 16));
      short8 ph, pl;
#pragma unroll
      for (int j = 0; j < 4; ++j) {
        unsigned short hh = f2bf(p0[j]);
        ph[j] = (short)hh;
        pl[j] = (short)f2bf(p0[j] - bf2f(hh));
        unsigned short hh2 = f2bf(p1[j]);
        ph[4 + j] = (short)hh2;
        pl[4 + j] = (short)f2bf(p1[j] - bf2f(hh2));
      }
#pragma unroll
      for (int ds = 0; ds < 4; ++ds) {
        int d = ds * 16 + ln;
        int voff = d * 128 + ((ks * 64 + quad * 16) ^ ((ln & 7) << 4));
        short8 vh = *reinterpret_cast<const short8*>(VhB + voff);
        short8 vl = *reinterpret_cast<const short8*>(VlB + voff);
        accO[ds] = __builtin_amdgcn_mfma_f32_16x16x32_bf16(ph, vh, accO[ds], 0, 0, 0);
        accO[ds] = __builtin_amdgcn_mfma_f32_16x16x32_bf16(pl, vh, accO[ds], 0, 0, 0);
        accO[ds] = __builtin_amdgcn_mfma_f32_16x16x32_bf16(ph, vl, accO[ds], 0, 0, 0);
      }
    }

    __syncthreads();  // all waves done reading tile kt
    if (kt < qt) {
      // Write prefetched tile kt+1 (vmcnt drains here; other block covers).
#pragma unroll
      for (int i = 0; i < 4; ++i) {
        int cid = tid + i * 256;
        int r = cid >> 4, c8 = (cid & 15) * 8;
        int ko = r * 256 + (((cid & 15) * 16) ^ ((r & 7) << 4));
        *reinterpret_cast<ushort8*>(KhB + ko) = skh[i];
        *reinterpret_cast<ushort8*>(KlB + ko) = skl[i];
      }
#pragma unroll
      for (int i = 0; i < 2; ++i) {
        int cid = tid + i * 256;
        int d = cid >> 3, t8 = (cid & 7) * 8;
        int vo = d * 128 + (((cid & 7) * 16) ^ ((d & 7) << 4));
        *reinterpret_cast<ushort8*>(VhB + vo) = svh[i];
        *reinterpret_cast<ushort8*>(VlB + vo) = svl[i];
      }
      // Issue prefetch for tile kt+2 (full compute phase of latency cover).
      if (kt + 2 <= qt) {
        int t0n = (kt + 2) * 64;
#pragma unroll
        for (int i = 0; i < 4; ++i) {
          int cid = tid + i * 256;
          int r = cid >> 4, c8 = (cid & 15) * 8;
          skh[i] = *reinterpret_cast<const ushort8*>(khb + ((size_t)(t0n + r)) * 128 + c8);
          skl[i] = *reinterpret_cast<const ushort8*>(klb + ((size_t)(t0n + r)) * 128 + c8);
        }
#pragma unroll
        for (int i = 0; i < 2; ++i) {
          int cid = tid + i * 256;
          int d = cid >> 3, t8 = (cid & 7) * 8;
          svh[i] = *reinterpret_cast<const ushort8*>(vhb + (size_t)d * S_ + t0n + t8);
          svl[i] = *reinterpret_cast<const ushort8*>(vlb + (size_t)d * S_ + t0n + t8);
        }
      }
      __syncthreads();  // tile kt+1 visible
    }
  }

  // Epilogue: accO -> Sc as Out[row][d], then the proven (r2,sub) GroupNorm.
  // All LDS traffic here is wave-private (rows w*16..w*16+15), barrier-free.
#pragma unroll
  for (int ds = 0; ds < 4; ++ds) {
#pragma unroll
    for (int rr = 0; rr < 4; ++rr) {
      int row = w * 16 + quad * 4 + rr;
      *reinterpret_cast<float*>(ScB + SCOFF(row, (ds * 16 + ln) * 4)) = accO[ds][rr];
    }
  }

  int r2 = tid >> 2;
  int sub = tid & 3;
  float a16[16];
#pragma unroll
  for (int c = 0; c < 4; ++c) {
    float4v t = *reinterpret_cast<const float4v*>(ScB + SCOFF(r2, sub * 64 + c * 16));
#pragma unroll
    for (int j = 0; j < 4; ++j) a16[c * 4 + j] = t[j];
  }

  float psum = 0.f, psq = 0.f;
#pragma unroll
  for (int i = 0; i < 16; ++i) { psum += a16[i]; psq += a16[i] * a16[i]; }
  gnred[r2][sub] = psum;
  gnred[r2][4 + sub] = psq;
  float sum = gnred[r2][0] + gnred[r2][1] + gnred[r2][2] + gnred[r2][3];
  float sq = gnred[r2][4] + gnred[r2][5] + gnred[r2][6] + gnred[r2][7];
  float mean = sum * (1.f / 64.f);
  float var = sq * (1.f / 64.f) - mean * mean;
  float rstd = rsqrtf(var + 1e-5f);

  size_t obase = ((size_t)(b * S_ + s0 + r2)) * HID_ + h * DH_ + sub * 16;
#pragma unroll
  for (int i = 0; i < 16; ++i) {
    float gw = gn_w[h * DH_ + sub * 16 + i];
    float gb = gn_b[h * DH_ + sub * 16 + i];
    retn[obase + i] = (a16[i] - mean) * rstd * gw + gb;
  }
}

// ---------------------------------------------------------------------------
// GEMM 1 (gate): unchanged, proven.
// ---------------------------------------------------------------------------
__global__ __launch_bounds__(256) void gemm_gate_kernel(
    const unsigned short* __restrict__ A, const unsigned short* __restrict__ Bt,
    const float* __restrict__ retn, unsigned short* __restrict__ pre_hi,
    unsigned short* __restrict__ pre_lo) {
  const int K = HID_;
  __shared__ __align__(16) unsigned short Al[128 * 56];
  __shared__ __align__(16) unsigned short Bl[128 * 56];

  int tid = threadIdx.x;
  int lane = tid & 63, ln = lane & 15, quad = lane >> 4;
  int w = tid >> 6, wm = w >> 1, wn = w & 1;
  int m0 = blockIdx.y * 128, n0 = blockIdx.x * 128;

  floatx4 acc[4][4];
#pragma unroll
  for (int i = 0; i < 4; ++i)
#pragma unroll
    for (int j = 0; j < 4; ++j) acc[i][j] = (floatx4){0.f, 0.f, 0.f, 0.f};

  for (int k0 = 0; k0 < K; k0 += 32) {
    __syncthreads();
#pragma unroll
    for (int i = 0; i < 2; ++i) {
      int cid = tid + i * 256;
      int r = cid >> 2, c8 = (cid & 3) * 8;
      *reinterpret_cast<ushort8*>(&Al[r * 56 + c8]) =
          *reinterpret_cast<const ushort8*>(A + (size_t)(m0 + r) * K + k0 + c8);
      *reinterpret_cast<ushort8*>(&Bl[r * 56 + c8]) =
          *reinterpret_cast<const ushort8*>(Bt + (size_t)(n0 + r) * K + k0 + c8);
    }
    __syncthreads();

    short8 af[4], bfr[4];
#pragma unroll
    for (int i = 0; i < 4; ++i) {
      af[i] = *reinterpret_cast<const short8*>(&Al[(wm * 64 + i * 16 + ln) * 56 + quad * 8]);
      bfr[i] = *reinterpret_cast<const short8*>(&Bl[(wn * 64 + i * 16 + ln) * 56 + quad * 8]);
    }
#pragma unroll
    for (int mi = 0; mi < 4; ++mi)
#pragma unroll
      for (int ni = 0; ni < 4; ++ni)
        acc[mi][ni] = __builtin_amdgcn_mfma_f32_16x16x32_bf16(af[mi], bfr[ni], acc[mi][ni], 0, 0, 0);
  }

#pragma unroll
  for (int mi = 0; mi < 4; ++mi) {
#pragma unroll
    for (int r = 0; r < 4; ++r) {
      int row = m0 + wm * 64 + mi * 16 + quad * 4 + r;
#pragma unroll
      for (int ni = 0; ni < 4; ++ni) {
        int col = n0 + wn * 64 + ni * 16 + ln;
        float g = acc[mi][ni][r];
        float val = g * (1.f / (1.f + __expf(-g))) + retn[(size_t)row * HID_ + col];
        unsigned short hh = f2bf(val);
        size_t oidx = (size_t)row * HID_ + col;
        pre_hi[oidx] = hh;
        pre_lo[oidx] = f2bf(val - bf2f(hh));
      }
    }
  }
}

// ---------------------------------------------------------------------------
// GEMM 2 (output): unchanged, proven.
// ---------------------------------------------------------------------------
__global__ __launch_bounds__(256) void gemm_out_kernel(
    const unsigned short* __restrict__ Ah, const unsigned short* __restrict__ Alo,
    const unsigned short* __restrict__ Bth, const unsigned short* __restrict__ Btlo,
    float* __restrict__ out_f) {
  const int K = HID_;
  __shared__ __align__(16) unsigned short AhS[128 * 56];
  __shared__ __align__(16) unsigned short AlS[128 * 56];
  __shared__ __align__(16) unsigned short BhS[128 * 56];
  __shared__ __align__(16) unsigned short BlS[128 * 56];

  int tid = threadIdx.x;
  int lane = tid & 63, ln = lane & 15, quad = lane >> 4;
  int w = tid >> 6, wm = w >> 1, wn = w & 1;
  int m0 = blockIdx.y * 128, n0 = blockIdx.x * 128;

  floatx4 acc[4][4];
#pragma unroll
  for (int i = 0; i < 4; ++i)
#pragma unroll
    for (int j = 0; j < 4; ++j) acc[i][j] = (floatx4){0.f, 0.f, 0.f, 0.f};

  for (int k0 = 0; k0 < K; k0 += 32) {
    __syncthreads();
#pragma unroll
    for (int i = 0; i < 2; ++i) {
      int cid = tid + i * 256;
      int r = cid >> 2, c8 = (cid & 3) * 8;
      size_t ga = (size_t)(m0 + r) * K + k0 + c8;
      size_t gb = (size_t)(n0 + r) * K + k0 + c8;
      *reinterpret_cast<ushort8*>(&AhS[r * 56 + c8]) = *reinterpret_cast<const ushort8*>(Ah + ga);
      *reinterpret_cast<ushort8*>(&AlS[r * 56 + c8]) = *reinterpret_cast<const ushort8*>(Alo + ga);
      *reinterpret_cast<ushort8*>(&BhS[r * 56 + c8]) = *reinterpret_cast<const ushort8*>(Bth + gb);
      *reinterpret_cast<ushort8*>(&BlS[r * 56 + c8]) = *reinterpret_cast<const ushort8*>(Btlo + gb);
    }
    __syncthreads();

    short8 afh[4], afl[4], bfh[4], bfl[4];
#pragma unroll
    for (int i = 0; i < 4; ++i) {
      int ao = (wm * 64 + i * 16 + ln) * 56 + quad * 8;
      int bo = (wn * 64 + i * 16 + ln) * 56 + quad * 8;
      afh[i] = *reinterpret_cast<const short8*>(&AhS[ao]);
      afl[i] = *reinterpret_cast<const short8*>(&AlS[ao]);
      bfh[i] = *reinterpret_cast<const short8*>(&BhS[bo]);
      bfl[i] = *reinterpret_cast<const short8*>(&BlS[bo]);
    }
#pragma unroll
    for (int mi = 0; mi < 4; ++mi)
#pragma unroll
      for (int ni = 0; ni < 4; ++ni) {
        floatx4 a = acc[mi][ni];
        a = __builtin_amdgcn_mfma_f32_16x16x32_bf16(afh[mi], bfh[ni], a, 0, 0, 0);
        a = __builtin_amdgcn_mfma_f32_16x16x32_bf16(afl[mi], bfh[ni], a, 0, 0, 0);
        a = __builtin_amdgcn_mfma_f32_16x16x32_bf16(afh[mi], bfl[ni], a, 0, 0, 0);
        acc[mi][ni] = a;
      }
  }

#pragma unroll
  for (int mi = 0; mi < 4; ++mi) {
#pragma unroll
    for (int r = 0; r < 4; ++r) {
      int row = m0 + wm * 64 + mi * 16 + quad * 4 + r;
#pragma unroll
      for (int ni = 0; ni < 4; ++ni) {
        int col = n0 + wn * 64 + ni * 16 + ln;
        out_f[(size_t)row * HID_ + col] = acc[mi][ni][r];
      }
    }
  }
}

// ---------------------------------------------------------------------------
extern "C" void kernel_launch(void* const* d_in, const int* in_sizes, int n_in,
                              void* d_out, int out_size, void* d_ws,
                              size_t ws_size, hipStream_t stream) {
  (void)in_sizes; (void)n_in; (void)out_size; (void)ws_size;
  const float* x = (const float*)d_in[0];
  const float* wq = (const float*)d_in[1];
  const float* bq = (const float*)d_in[2];
  const float* wk = (const float*)d_in[3];
  const float* bk = (const float*)d_in[4];
  const float* wv = (const float*)d_in[5];
  const float* theta = (const float*)d_in[6];
  const float* gn_w = (const float*)d_in[7];
  const float* gn_b = (const float*)d_in[8];
  const float* w1 = (const float*)d_in[9];
  const float* w2 = (const float*)d_in[10];

  const size_t MB = 1024 * 1024;
  char* ws = (char*)d_ws;
  unsigned short* x_bf   = (unsigned short*)(ws + 0 * MB);    //  8 MiB
  unsigned short* w1t    = (unsigned short*)(ws + 8 * MB);    //  2 MiB
  unsigned short* w2t_hi = (unsigned short*)(ws + 10 * MB);   //  2 MiB
  unsigned short* w2t_lo = (unsigned short*)(ws + 12 * MB);   //  2 MiB
  unsigned short* q_h    = (unsigned short*)(ws + 14 * MB);   //  8 MiB (1 batch)
  unsigned short* q_l    = (unsigned short*)(ws + 22 * MB);   //  8 MiB
  unsigned short* k_h    = (unsigned short*)(ws + 30 * MB);   //  8 MiB
  unsigned short* k_l    = (unsigned short*)(ws + 38 * MB);   //  8 MiB
  unsigned short* v_th   = (unsigned short*)(ws + 46 * MB);   //  4 MiB
  unsigned short* v_tl   = (unsigned short*)(ws + 50 * MB);   //  4 MiB
  float*          retn   = (float*)(ws + 54 * MB);            // 16 MiB (both batches)
  unsigned short* pre_hi = (unsigned short*)(ws + 14 * MB);   //  8 MiB (alias q_h, dead by then)
  unsigned short* pre_lo = (unsigned short*)(ws + 22 * MB);   //  8 MiB (alias q_l)
  float* out = (float*)d_out;

  convert_kernel<<<dim3(24576), 256, 0, stream>>>(x, w1, w2, x_bf, w1t, w2t_hi, w2t_lo);
  for (int b = 0; b < B_; ++b) {
    qkv_kernel<<<dim3(S_ / 64, H_), 256, 0, stream>>>(
        x, wq, bq, wk, bk, wv, theta, q_h, q_l, k_h, k_l, v_th, v_tl, b);
    retention_fold_kernel<<<dim3(512), 256, 0, stream>>>(
        q_h, q_l, k_h, k_l, v_th, v_tl, gn_w, gn_b, retn, b);
  }
  gemm_gate_kernel<<<dim3(HID_ / 128, (B_ * S_) / 128), 256, 0, stream>>>(
      x_bf, w1t, retn, pre_hi, pre_lo);
  gemm_out_kernel<<<dim3(HID_ / 128, (B_ * S_) / 128), 256, 0, stream>>>(
      pre_hi, pre_lo, w2t_hi, w2t_lo, out);
}

// Round 6
// 345.434 us; speedup vs baseline: 1.1513x; 1.0948x over previous
//
#include <hip/hip_runtime.h>
#include <cstdint>
#include <cstddef>

#define B_ 2
#define S_ 2048
#define HID_ 1024
#define H_ 16
#define DH_ 64

typedef __attribute__((ext_vector_type(8))) short short8;
typedef __attribute__((ext_vector_type(8))) unsigned short ushort8;
typedef __attribute__((ext_vector_type(4))) unsigned short ushort4v;
typedef __attribute__((ext_vector_type(4))) float floatx4;
typedef __attribute__((ext_vector_type(4))) float float4v;

static __device__ __forceinline__ unsigned short f2bf(float f) {
  unsigned int u = __float_as_uint(f);
  u += 0x7fffu + ((u >> 16) & 1u);
  return (unsigned short)(u >> 16);
}
static __device__ __forceinline__ float bf2f(unsigned short h) {
  return __uint_as_float(((unsigned int)h) << 16);
}

// ---------------------------------------------------------------------------
// Kernel 0: conversions. (unchanged, proven)
// ---------------------------------------------------------------------------
__global__ __launch_bounds__(256) void convert_kernel(
    const float* __restrict__ x, const float* __restrict__ w1,
    const float* __restrict__ w2, unsigned short* __restrict__ x_bf,
    unsigned short* __restrict__ w1t, unsigned short* __restrict__ w2t_hi,
    unsigned short* __restrict__ w2t_lo) {
  const int NX = B_ * S_ * HID_;
  const int NW = HID_ * HID_;
  int idx = blockIdx.x * 256 + threadIdx.x;
  if (idx < NX) {
    x_bf[idx] = f2bf(x[idx]);
  } else if (idx < NX + NW) {
    int i = idx - NX;
    int n = i >> 10, k = i & 1023;
    w1t[i] = f2bf(w1[k * HID_ + n]);
  } else if (idx < NX + 2 * NW) {
    int i = idx - NX - NW;
    int n = i >> 10, k = i & 1023;
    float v = w2[k * HID_ + n];
    unsigned short h = f2bf(v);
    w2t_hi[i] = h;
    w2t_lo[i] = f2bf(v - bf2f(h));
  }
}

// ---------------------------------------------------------------------------
// Kernel A: per-head QKV projection + bias + rotary. (unchanged, proven)
// ---------------------------------------------------------------------------
__global__ __launch_bounds__(256) void qkv_kernel(
    const float* __restrict__ x, const float* __restrict__ wq,
    const float* __restrict__ bq, const float* __restrict__ wk,
    const float* __restrict__ bk, const float* __restrict__ wv,
    const float* __restrict__ theta,
    unsigned short* __restrict__ q_h, unsigned short* __restrict__ q_l,
    unsigned short* __restrict__ k_h, unsigned short* __restrict__ k_l,
    unsigned short* __restrict__ v_th, unsigned short* __restrict__ v_tl,
    int b) {
  __shared__ __align__(16) float xs[64 * 68];
  __shared__ __align__(16) float wqs[64 * 68];
  __shared__ __align__(16) float wks[64 * 68];
  __shared__ __align__(16) float wvs[64 * 68];

  int tid = threadIdx.x;
  int st = blockIdx.x, h = blockIdx.y;
  int s0 = st * 64;

#pragma unroll
  for (int i = 0; i < 4; ++i) {
    int cid = tid + i * 256;
    int r = cid >> 4, c4 = (cid & 15) * 4;
    *reinterpret_cast<float4v*>(&xs[r * 68 + c4]) =
        *reinterpret_cast<const float4v*>(x + ((size_t)(b * S_ + s0 + r)) * HID_ + h * DH_ + c4);
  }
#pragma unroll
  for (int i = 0; i < 4; ++i) {
    int cid = tid + i * 256;
    int d = cid >> 4, c4 = (cid & 15) * 4;
    *reinterpret_cast<float4v*>(&wqs[d * 68 + c4]) =
        *reinterpret_cast<const float4v*>(wq + (size_t)(h * DH_ + d) * DH_ + c4);
    *reinterpret_cast<float4v*>(&wks[d * 68 + c4]) =
        *reinterpret_cast<const float4v*>(wk + (size_t)(h * DH_ + d) * DH_ + c4);
    *reinterpret_cast<float4v*>(&wvs[d * 68 + c4]) =
        *reinterpret_cast<const float4v*>(wv + (size_t)(h * DH_ + d) * DH_ + c4);
  }
  __syncthreads();

  int rg = tid >> 3;
  int cg = tid & 7;
  int r0 = rg * 2, c0 = cg * 8;

  float aq[2][8], ak[2][8], av[2][8];
#pragma unroll
  for (int i = 0; i < 2; ++i)
#pragma unroll
    for (int j = 0; j < 8; ++j) { aq[i][j] = 0.f; ak[i][j] = 0.f; av[i][j] = 0.f; }

  for (int d = 0; d < 64; ++d) {
    float x0 = xs[(r0 + 0) * 68 + d];
    float x1 = xs[(r0 + 1) * 68 + d];
#pragma unroll
    for (int j = 0; j < 8; ++j) {
      float wqv = wqs[d * 68 + c0 + j];
      float wkv = wks[d * 68 + c0 + j];
      float wvv = wvs[d * 68 + c0 + j];
      aq[0][j] += x0 * wqv; aq[1][j] += x1 * wqv;
      ak[0][j] += x0 * wkv; ak[1][j] += x1 * wkv;
      av[0][j] += x0 * wvv; av[1][j] += x1 * wvv;
    }
  }

  float thv[8], bqv[8], bkv[8];
#pragma unroll
  for (int j = 0; j < 8; ++j) {
    thv[j] = theta[h * DH_ + c0 + j];
    bqv[j] = bq[h * DH_ + c0 + j];
    bkv[j] = bk[h * DH_ + c0 + j];
  }

  // Reuse xs/wqs LDS as bf16 V-transpose staging (all reads of them are done).
  __syncthreads();
  unsigned short* VtH = reinterpret_cast<unsigned short*>(xs);   // [64 d][72]
  unsigned short* VtL = reinterpret_cast<unsigned short*>(wqs);  // [64 d][72]

#pragma unroll
  for (int i = 0; i < 2; ++i) {
    int s = s0 + r0 + i;
    size_t qb = ((size_t)h * S_ + s) * 128;
    ushort8 qch, qcl, qsh, qsl, kch, kcl, ksh, ksl;
#pragma unroll
    for (int j = 0; j < 8; ++j) {
      float q = aq[i][j] + bqv[j];
      float k = ak[i][j] + bkv[j];
      float ang = (float)s * thv[j];
      float cs = cosf(ang), sn = sinf(ang);
      float qc = q * cs, qs = q * sn;
      unsigned short hq1 = f2bf(qc);
      qch[j] = hq1;
      qcl[j] = f2bf(qc - bf2f(hq1));
      unsigned short hq2 = f2bf(qs);
      qsh[j] = hq2;
      qsl[j] = f2bf(qs - bf2f(hq2));
      float kc = k * cs, ksn = k * sn;
      unsigned short h1 = f2bf(kc);
      kch[j] = h1;
      kcl[j] = f2bf(kc - bf2f(h1));
      unsigned short h2 = f2bf(ksn);
      ksh[j] = h2;
      ksl[j] = f2bf(ksn - bf2f(h2));
      float vv = av[i][j];
      unsigned short vh1 = f2bf(vv);
      VtH[(c0 + j) * 72 + (r0 + i)] = vh1;
      VtL[(c0 + j) * 72 + (r0 + i)] = f2bf(vv - bf2f(vh1));
    }
    *reinterpret_cast<ushort8*>(q_h + qb + c0) = qch;
    *reinterpret_cast<ushort8*>(q_h + qb + 64 + c0) = qsh;
    *reinterpret_cast<ushort8*>(q_l + qb + c0) = qcl;
    *reinterpret_cast<ushort8*>(q_l + qb + 64 + c0) = qsl;
    *reinterpret_cast<ushort8*>(k_h + qb + c0) = kch;
    *reinterpret_cast<ushort8*>(k_h + qb + 64 + c0) = ksh;
    *reinterpret_cast<ushort8*>(k_l + qb + c0) = kcl;
    *reinterpret_cast<ushort8*>(k_l + qb + 64 + c0) = ksl;
  }
  __syncthreads();
  // Coalesced transposed store: v_t[h][d][S]
#pragma unroll
  for (int i = 0; i < 2; ++i) {
    int cid = tid + i * 256;
    int d = cid >> 3, t8 = (cid & 7) * 8;
    size_t gb = ((size_t)(h * 64 + d)) * S_ + s0 + t8;
    *reinterpret_cast<ushort8*>(v_th + gb) = *reinterpret_cast<const ushort8*>(&VtH[d * 72 + t8]);
    *reinterpret_cast<ushort8*>(v_tl + gb) = *reinterpret_cast<const ushort8*>(&VtL[d * 72 + t8]);
  }
}

// ---------------------------------------------------------------------------
// Kernel B: retention v4 — split-kt + dynamic backfill (the r5 lesson: exact
// 512-block grids leave no pending work; freed slots go idle and the long
// block of each pair runs alone at 1 wave/SIMD).
//  - Per (h, qt): TWO blocks (halves of the kt range, each <=16 iters).
//    Grid 1024/batch, 512 resident + 512 pending -> the CP backfills freed
//    slots; CUs sustain 2 blocks (2 waves/SIMD) nearly the whole dispatch.
//  - Heavy-first order (qt = 31 - (f>>5)); XCD-affinity decode kept (f&7).
//  - Halves write raw fp32 partial accO (partials add linearly); GroupNorm
//    moved to a small combine kernel. LDS 64 KiB -> 2 blocks/CU.
//  - Loop body (swizzles, factored decay, MFMA indexing, reg-prefetch,
//    2 barriers/iter): byte-identical to the passing r5 kernel.
// ---------------------------------------------------------------------------
#define SCOFF(row, colb)   ((row) * 256 + ((colb) ^ (((row) & 7) << 4)))

__global__ __launch_bounds__(256, 2) void retention_split_kernel(
    const unsigned short* __restrict__ q_h, const unsigned short* __restrict__ q_l,
    const unsigned short* __restrict__ k_h, const unsigned short* __restrict__ k_l,
    const unsigned short* __restrict__ v_th, const unsigned short* __restrict__ v_tl,
    float* __restrict__ partial) {
  __shared__ __align__(16) unsigned short Kh[64 * 128];  // 16 KiB swizzled
  __shared__ __align__(16) unsigned short Kl[64 * 128];  // 16 KiB
  __shared__ __align__(16) unsigned short Vh[64 * 64];   //  8 KiB [d][t]
  __shared__ __align__(16) unsigned short Vl[64 * 64];   //  8 KiB
  __shared__ __align__(16) float Sc[64 * 64];            // 16 KiB swizzled

  char* KhB = (char*)Kh;
  char* KlB = (char*)Kl;
  char* VhB = (char*)Vh;
  char* VlB = (char*)Vl;
  char* ScB = (char*)Sc;

  int tid = threadIdx.x;
  int w = tid >> 6;
  int lane = tid & 63, ln = lane & 15, quad = lane >> 4;
  // Decode (bijective on [0,1024)): xcd-affine h, heavy-first qt, half bit.
  int f = blockIdx.x;
  int h = ((f & 7) << 1) | ((f >> 3) & 1);
  int half = (f >> 4) & 1;
  int qt = 31 - (f >> 5);
  int s0 = qt * 64;
  int prow = quad * 4;

  // kt range for this half: [kt0, kt1). m = ceil((qt+1)/2).
  int m = (qt + 2) >> 1;
  int kt0 = half ? m : 0;
  int kt1 = half ? (qt + 1) : m;

  const float lo_c = -6.2383246250395075f, hi_c = -3.4657359027997265f;
  float gam = 1.f - __expf(lo_c + (hi_c - lo_c) * ((float)h * (1.f / 15.f)));
  float logg = __logf(gam);

  // Factored decay: gamma^(s-t) = gamma^(64*(qt-kt)) * gamma^lrow * gamma^-lcol
  float rowf[4], colf[4];
#pragma unroll
  for (int rr = 0; rr < 4; ++rr)
    rowf[rr] = __expf((float)(w * 16 + prow + rr) * logg);
#pragma unroll
  for (int ns = 0; ns < 4; ++ns)
    colf[ns] = __expf(-(float)(ns * 16 + ln) * logg);

  const unsigned short* khb = k_h + (size_t)h * S_ * 128;
  const unsigned short* klb = k_l + (size_t)h * S_ * 128;
  const unsigned short* vhb = v_th + (size_t)h * 64 * S_;
  const unsigned short* vlb = v_tl + (size_t)h * 64 * S_;

  // Q fragments (A-layout), precomputed bf16 hi/lo.
  int sQ = s0 + w * 16 + ln;
  const unsigned short* qhp = q_h + ((size_t)h * S_ + sQ) * 128 + quad * 8;
  const unsigned short* qlp = q_l + ((size_t)h * S_ + sQ) * 128 + quad * 8;
  short8 qfh[4], qfl[4];
#pragma unroll
  for (int c = 0; c < 4; ++c) {
    qfh[c] = *reinterpret_cast<const short8*>(qhp + c * 32);
    qfl[c] = *reinterpret_cast<const short8*>(qlp + c * 32);
  }

  floatx4 accO[4];
#pragma unroll
  for (int i = 0; i < 4; ++i) accO[i] = (floatx4){0.f, 0.f, 0.f, 0.f};

  // Prologue: load tile kt0 -> regs -> LDS; prefetch tile kt0+1 into regs.
  ushort8 skh[4], skl[4], svh[2], svl[2];
  int t00 = kt0 * 64;
#pragma unroll
  for (int i = 0; i < 4; ++i) {
    int cid = tid + i * 256;
    int r = cid >> 4, c8 = (cid & 15) * 8;
    skh[i] = *reinterpret_cast<const ushort8*>(khb + ((size_t)(t00 + r)) * 128 + c8);
    skl[i] = *reinterpret_cast<const ushort8*>(klb + ((size_t)(t00 + r)) * 128 + c8);
  }
#pragma unroll
  for (int i = 0; i < 2; ++i) {
    int cid = tid + i * 256;
    int d = cid >> 3, t8 = (cid & 7) * 8;
    svh[i] = *reinterpret_cast<const ushort8*>(vhb + (size_t)d * S_ + t00 + t8);
    svl[i] = *reinterpret_cast<const ushort8*>(vlb + (size_t)d * S_ + t00 + t8);
  }
#pragma unroll
  for (int i = 0; i < 4; ++i) {
    int cid = tid + i * 256;
    int r = cid >> 4;
    int ko = r * 256 + (((cid & 15) * 16) ^ ((r & 7) << 4));
    *reinterpret_cast<ushort8*>(KhB + ko) = skh[i];
    *reinterpret_cast<ushort8*>(KlB + ko) = skl[i];
  }
#pragma unroll
  for (int i = 0; i < 2; ++i) {
    int cid = tid + i * 256;
    int d = cid >> 3;
    int vo = d * 128 + (((cid & 7) * 16) ^ ((d & 7) << 4));
    *reinterpret_cast<ushort8*>(VhB + vo) = svh[i];
    *reinterpret_cast<ushort8*>(VlB + vo) = svl[i];
  }
  if (kt0 + 1 < kt1) {
    int t01 = (kt0 + 1) * 64;
#pragma unroll
    for (int i = 0; i < 4; ++i) {
      int cid = tid + i * 256;
      int r = cid >> 4, c8 = (cid & 15) * 8;
      skh[i] = *reinterpret_cast<const ushort8*>(khb + ((size_t)(t01 + r)) * 128 + c8);
      skl[i] = *reinterpret_cast<const ushort8*>(klb + ((size_t)(t01 + r)) * 128 + c8);
    }
#pragma unroll
    for (int i = 0; i < 2; ++i) {
      int cid = tid + i * 256;
      int d = cid >> 3, t8 = (cid & 7) * 8;
      svh[i] = *reinterpret_cast<const ushort8*>(vhb + (size_t)d * S_ + t01 + t8);
      svl[i] = *reinterpret_cast<const ushort8*>(vlb + (size_t)d * S_ + t01 + t8);
    }
  }
  __syncthreads();

  for (int kt = kt0; kt < kt1; ++kt) {
    // QK^T split-MFMA (proven structure, swizzled K reads)
    floatx4 accS[4];
#pragma unroll
    for (int ns = 0; ns < 4; ++ns) {
      floatx4 a = (floatx4){0.f, 0.f, 0.f, 0.f};
      int row = ns * 16 + ln;
#pragma unroll
      for (int ks = 0; ks < 4; ++ks) {
        int off = row * 256 + ((ks * 64 + quad * 16) ^ ((ln & 7) << 4));
        short8 kh = *reinterpret_cast<const short8*>(KhB + off);
        short8 kl = *reinterpret_cast<const short8*>(KlB + off);
        a = __builtin_amdgcn_mfma_f32_16x16x32_bf16(qfh[ks], kh, a, 0, 0, 0);
        a = __builtin_amdgcn_mfma_f32_16x16x32_bf16(qfl[ks], kh, a, 0, 0, 0);
        a = __builtin_amdgcn_mfma_f32_16x16x32_bf16(qfh[ks], kl, a, 0, 0, 0);
      }
      accS[ns] = a;
    }

    // Factored decay (+ causal select only on the diagonal tile) -> Sc.
    float tf = __expf((float)(64 * (qt - kt)) * logg);
    float trf[4];
#pragma unroll
    for (int rr = 0; rr < 4; ++rr) trf[rr] = tf * rowf[rr];
    if (kt < qt) {
#pragma unroll
      for (int ns = 0; ns < 4; ++ns) {
        int col = ns * 16 + ln;
#pragma unroll
        for (int rr = 0; rr < 4; ++rr) {
          int row = w * 16 + prow + rr;
          *reinterpret_cast<float*>(ScB + SCOFF(row, col * 4)) =
              accS[ns][rr] * trf[rr] * colf[ns];
        }
      }
    } else {
#pragma unroll
      for (int ns = 0; ns < 4; ++ns) {
        int col = ns * 16 + ln;
#pragma unroll
        for (int rr = 0; rr < 4; ++rr) {
          int row = w * 16 + prow + rr;
          float v = accS[ns][rr] * trf[rr] * colf[ns];
          *reinterpret_cast<float*>(ScB + SCOFF(row, col * 4)) =
              (row >= col) ? v : 0.f;
        }
      }
    }

    // PV split-MFMA. Sc rows read here are written by THIS wave only
    // (in-order DS within a wave; no barrier needed).
#pragma unroll
    for (int ks = 0; ks < 2; ++ks) {
      int prw = w * 16 + ln;
      int cb = ks * 128 + quad * 32;
      float4v p0 = *reinterpret_cast<const float4v*>(ScB + SCOFF(prw, cb));
      float4v p1 = *reinterpret_cast<const float4v*>(ScB + SCOFF(prw, cb + 16));
      short8 ph, pl;
#pragma unroll
      for (int j = 0; j < 4; ++j) {
        unsigned short hh = f2bf(p0[j]);
        ph[j] = (short)hh;
        pl[j] = (short)f2bf(p0[j] - bf2f(hh));
        unsigned short hh2 = f2bf(p1[j]);
        ph[4 + j] = (short)hh2;
        pl[4 + j] = (short)f2bf(p1[j] - bf2f(hh2));
      }
#pragma unroll
      for (int ds = 0; ds < 4; ++ds) {
        int d = ds * 16 + ln;
        int voff = d * 128 + ((ks * 64 + quad * 16) ^ ((ln & 7) << 4));
        short8 vh = *reinterpret_cast<const short8*>(VhB + voff);
        short8 vl = *reinterpret_cast<const short8*>(VlB + voff);
        accO[ds] = __builtin_amdgcn_mfma_f32_16x16x32_bf16(ph, vh, accO[ds], 0, 0, 0);
        accO[ds] = __builtin_amdgcn_mfma_f32_16x16x32_bf16(pl, vh, accO[ds], 0, 0, 0);
        accO[ds] = __builtin_amdgcn_mfma_f32_16x16x32_bf16(ph, vl, accO[ds], 0, 0, 0);
      }
    }

    __syncthreads();  // all waves done reading tile kt
    if (kt + 1 < kt1) {
      // Write prefetched tile kt+1 (vmcnt drains here; co-resident block covers).
#pragma unroll
      for (int i = 0; i < 4; ++i) {
        int cid = tid + i * 256;
        int r = cid >> 4;
        int ko = r * 256 + (((cid & 15) * 16) ^ ((r & 7) << 4));
        *reinterpret_cast<ushort8*>(KhB + ko) = skh[i];
        *reinterpret_cast<ushort8*>(KlB + ko) = skl[i];
      }
#pragma unroll
      for (int i = 0; i < 2; ++i) {
        int cid = tid + i * 256;
        int d = cid >> 3;
        int vo = d * 128 + (((cid & 7) * 16) ^ ((d & 7) << 4));
        *reinterpret_cast<ushort8*>(VhB + vo) = svh[i];
        *reinterpret_cast<ushort8*>(VlB + vo) = svl[i];
      }
      // Issue prefetch for tile kt+2 (full compute phase of latency cover).
      if (kt + 2 < kt1) {
        int t0n = (kt + 2) * 64;
#pragma unroll
        for (int i = 0; i < 4; ++i) {
          int cid = tid + i * 256;
          int r = cid >> 4, c8 = (cid & 15) * 8;
          skh[i] = *reinterpret_cast<const ushort8*>(khb + ((size_t)(t0n + r)) * 128 + c8);
          skl[i] = *reinterpret_cast<const ushort8*>(klb + ((size_t)(t0n + r)) * 128 + c8);
        }
#pragma unroll
        for (int i = 0; i < 2; ++i) {
          int cid = tid + i * 256;
          int d = cid >> 3, t8 = (cid & 7) * 8;
          svh[i] = *reinterpret_cast<const ushort8*>(vhb + (size_t)d * S_ + t0n + t8);
          svl[i] = *reinterpret_cast<const ushort8*>(vlb + (size_t)d * S_ + t0n + t8);
        }
      }
      __syncthreads();  // tile kt+1 visible
    }
  }

  // Epilogue: store raw fp32 partial accO (C-layout scatter, 16 KB/block).
  float* pout = partial + ((size_t)(((h * 32 + qt) << 1) + half)) * 4096;
#pragma unroll
  for (int ds = 0; ds < 4; ++ds) {
#pragma unroll
    for (int rr = 0; rr < 4; ++rr) {
      pout[(w * 16 + quad * 4 + rr) * 64 + ds * 16 + ln] = accO[ds][rr];
    }
  }
}

// ---------------------------------------------------------------------------
// Kernel B2: combine halves + GroupNorm (proven (r2,sub) mapping). 512 blocks.
// ---------------------------------------------------------------------------
__global__ __launch_bounds__(256) void combine_gn_kernel(
    const float* __restrict__ partial, const float* __restrict__ gn_w,
    const float* __restrict__ gn_b, float* __restrict__ retn, int b) {
  __shared__ float gnred[64][8];
  int tid = threadIdx.x;
  int qi = blockIdx.x;            // qi = h*32 + qt
  int h = qi >> 5, qt = qi & 31;
  const float* p0 = partial + (size_t)qi * 8192;
  const float* p1 = p0 + 4096;

  int r2 = tid >> 2;
  int sub = tid & 3;
  float a16[16];
#pragma unroll
  for (int c = 0; c < 4; ++c) {
    float4v va = *reinterpret_cast<const float4v*>(p0 + r2 * 64 + sub * 16 + c * 4);
    float4v vb = *reinterpret_cast<const float4v*>(p1 + r2 * 64 + sub * 16 + c * 4);
#pragma unroll
    for (int j = 0; j < 4; ++j) a16[c * 4 + j] = va[j] + vb[j];
  }

  float psum = 0.f, psq = 0.f;
#pragma unroll
  for (int i = 0; i < 16; ++i) { psum += a16[i]; psq += a16[i] * a16[i]; }
  gnred[r2][sub] = psum;
  gnred[r2][4 + sub] = psq;
  float sum = gnred[r2][0] + gnred[r2][1] + gnred[r2][2] + gnred[r2][3];
  float sq = gnred[r2][4] + gnred[r2][5] + gnred[r2][6] + gnred[r2][7];
  float mean = sum * (1.f / 64.f);
  float var = sq * (1.f / 64.f) - mean * mean;
  float rstd = rsqrtf(var + 1e-5f);

  size_t obase = ((size_t)(b * S_ + qt * 64 + r2)) * HID_ + h * DH_ + sub * 16;
#pragma unroll
  for (int i = 0; i < 16; ++i) {
    float gw = gn_w[h * DH_ + sub * 16 + i];
    float gb = gn_b[h * DH_ + sub * 16 + i];
    retn[obase + i] = (a16[i] - mean) * rstd * gw + gb;
  }
}

// ---------------------------------------------------------------------------
// GEMM 1 (gate): unchanged, proven.
// ---------------------------------------------------------------------------
__global__ __launch_bounds__(256) void gemm_gate_kernel(
    const unsigned short* __restrict__ A, const unsigned short* __restrict__ Bt,
    const float* __restrict__ retn, unsigned short* __restrict__ pre_hi,
    unsigned short* __restrict__ pre_lo) {
  const int K = HID_;
  __shared__ __align__(16) unsigned short Al[128 * 56];
  __shared__ __align__(16) unsigned short Bl[128 * 56];

  int tid = threadIdx.x;
  int lane = tid & 63, ln = lane & 15, quad = lane >> 4;
  int w = tid >> 6, wm = w >> 1, wn = w & 1;
  int m0 = blockIdx.y * 128, n0 = blockIdx.x * 128;

  floatx4 acc[4][4];
#pragma unroll
  for (int i = 0; i < 4; ++i)
#pragma unroll
    for (int j = 0; j < 4; ++j) acc[i][j] = (floatx4){0.f, 0.f, 0.f, 0.f};

  for (int k0 = 0; k0 < K; k0 += 32) {
    __syncthreads();
#pragma unroll
    for (int i = 0; i < 2; ++i) {
      int cid = tid + i * 256;
      int r = cid >> 2, c8 = (cid & 3) * 8;
      *reinterpret_cast<ushort8*>(&Al[r * 56 + c8]) =
          *reinterpret_cast<const ushort8*>(A + (size_t)(m0 + r) * K + k0 + c8);
      *reinterpret_cast<ushort8*>(&Bl[r * 56 + c8]) =
          *reinterpret_cast<const ushort8*>(Bt + (size_t)(n0 + r) * K + k0 + c8);
    }
    __syncthreads();

    short8 af[4], bfr[4];
#pragma unroll
    for (int i = 0; i < 4; ++i) {
      af[i] = *reinterpret_cast<const short8*>(&Al[(wm * 64 + i * 16 + ln) * 56 + quad * 8]);
      bfr[i] = *reinterpret_cast<const short8*>(&Bl[(wn * 64 + i * 16 + ln) * 56 + quad * 8]);
    }
#pragma unroll
    for (int mi = 0; mi < 4; ++mi)
#pragma unroll
      for (int ni = 0; ni < 4; ++ni)
        acc[mi][ni] = __builtin_amdgcn_mfma_f32_16x16x32_bf16(af[mi], bfr[ni], acc[mi][ni], 0, 0, 0);
  }

#pragma unroll
  for (int mi = 0; mi < 4; ++mi) {
#pragma unroll
    for (int r = 0; r < 4; ++r) {
      int row = m0 + wm * 64 + mi * 16 + quad * 4 + r;
#pragma unroll
      for (int ni = 0; ni < 4; ++ni) {
        int col = n0 + wn * 64 + ni * 16 + ln;
        float g = acc[mi][ni][r];
        float val = g * (1.f / (1.f + __expf(-g))) + retn[(size_t)row * HID_ + col];
        unsigned short hh = f2bf(val);
        size_t oidx = (size_t)row * HID_ + col;
        pre_hi[oidx] = hh;
        pre_lo[oidx] = f2bf(val - bf2f(hh));
      }
    }
  }
}

// ---------------------------------------------------------------------------
// GEMM 2 (output): unchanged, proven.
// ---------------------------------------------------------------------------
__global__ __launch_bounds__(256) void gemm_out_kernel(
    const unsigned short* __restrict__ Ah, const unsigned short* __restrict__ Alo,
    const unsigned short* __restrict__ Bth, const unsigned short* __restrict__ Btlo,
    float* __restrict__ out_f) {
  const int K = HID_;
  __shared__ __align__(16) unsigned short AhS[128 * 56];
  __shared__ __align__(16) unsigned short AlS[128 * 56];
  __shared__ __align__(16) unsigned short BhS[128 * 56];
  __shared__ __align__(16) unsigned short BlS[128 * 56];

  int tid = threadIdx.x;
  int lane = tid & 63, ln = lane & 15, quad = lane >> 4;
  int w = tid >> 6, wm = w >> 1, wn = w & 1;
  int m0 = blockIdx.y * 128, n0 = blockIdx.x * 128;

  floatx4 acc[4][4];
#pragma unroll
  for (int i = 0; i < 4; ++i)
#pragma unroll
    for (int j = 0; j < 4; ++j) acc[i][j] = (floatx4){0.f, 0.f, 0.f, 0.f};

  for (int k0 = 0; k0 < K; k0 += 32) {
    __syncthreads();
#pragma unroll
    for (int i = 0; i < 2; ++i) {
      int cid = tid + i * 256;
      int r = cid >> 2, c8 = (cid & 3) * 8;
      size_t ga = (size_t)(m0 + r) * K + k0 + c8;
      size_t gb = (size_t)(n0 + r) * K + k0 + c8;
      *reinterpret_cast<ushort8*>(&AhS[r * 56 + c8]) = *reinterpret_cast<const ushort8*>(Ah + ga);
      *reinterpret_cast<ushort8*>(&AlS[r * 56 + c8]) = *reinterpret_cast<const ushort8*>(Alo + ga);
      *reinterpret_cast<ushort8*>(&BhS[r * 56 + c8]) = *reinterpret_cast<const ushort8*>(Bth + gb);
      *reinterpret_cast<ushort8*>(&BlS[r * 56 + c8]) = *reinterpret_cast<const ushort8*>(Btlo + gb);
    }
    __syncthreads();

    short8 afh[4], afl[4], bfh[4], bfl[4];
#pragma unroll
    for (int i = 0; i < 4; ++i) {
      int ao = (wm * 64 + i * 16 + ln) * 56 + quad * 8;
      int bo = (wn * 64 + i * 16 + ln) * 56 + quad * 8;
      afh[i] = *reinterpret_cast<const short8*>(&AhS[ao]);
      afl[i] = *reinterpret_cast<const short8*>(&AlS[ao]);
      bfh[i] = *reinterpret_cast<const short8*>(&BhS[bo]);
      bfl[i] = *reinterpret_cast<const short8*>(&BlS[bo]);
    }
#pragma unroll
    for (int mi = 0; mi < 4; ++mi)
#pragma unroll
      for (int ni = 0; ni < 4; ++ni) {
        floatx4 a = acc[mi][ni];
        a = __builtin_amdgcn_mfma_f32_16x16x32_bf16(afh[mi], bfh[ni], a, 0, 0, 0);
        a = __builtin_amdgcn_mfma_f32_16x16x32_bf16(afl[mi], bfh[ni], a, 0, 0, 0);
        a = __builtin_amdgcn_mfma_f32_16x16x32_bf16(afh[mi], bfl[ni], a, 0, 0, 0);
        acc[mi][ni] = a;
      }
  }

#pragma unroll
  for (int mi = 0; mi < 4; ++mi) {
#pragma unroll
    for (int r = 0; r < 4; ++r) {
      int row = m0 + wm * 64 + mi * 16 + quad * 4 + r;
#pragma unroll
      for (int ni = 0; ni < 4; ++ni) {
        int col = n0 + wn * 64 + ni * 16 + ln;
        out_f[(size_t)row * HID_ + col] = acc[mi][ni][r];
      }
    }
  }
}

// ---------------------------------------------------------------------------
extern "C" void kernel_launch(void* const* d_in, const int* in_sizes, int n_in,
                              void* d_out, int out_size, void* d_ws,
                              size_t ws_size, hipStream_t stream) {
  (void)in_sizes; (void)n_in; (void)out_size; (void)ws_size;
  const float* x = (const float*)d_in[0];
  const float* wq = (const float*)d_in[1];
  const float* bq = (const float*)d_in[2];
  const float* wk = (const float*)d_in[3];
  const float* bk = (const float*)d_in[4];
  const float* wv = (const float*)d_in[5];
  const float* theta = (const float*)d_in[6];
  const float* gn_w = (const float*)d_in[7];
  const float* gn_b = (const float*)d_in[8];
  const float* w1 = (const float*)d_in[9];
  const float* w2 = (const float*)d_in[10];

  const size_t MB = 1024 * 1024;
  char* ws = (char*)d_ws;
  unsigned short* x_bf   = (unsigned short*)(ws + 0 * MB);    //  8 MiB
  unsigned short* w1t    = (unsigned short*)(ws + 8 * MB);    //  2 MiB
  unsigned short* w2t_hi = (unsigned short*)(ws + 10 * MB);   //  2 MiB
  unsigned short* w2t_lo = (unsigned short*)(ws + 12 * MB);   //  2 MiB
  unsigned short* q_h    = (unsigned short*)(ws + 14 * MB);   //  8 MiB (1 batch)
  unsigned short* q_l    = (unsigned short*)(ws + 22 * MB);   //  8 MiB
  unsigned short* k_h    = (unsigned short*)(ws + 30 * MB);   //  8 MiB
  unsigned short* k_l    = (unsigned short*)(ws + 38 * MB);   //  8 MiB
  unsigned short* v_th   = (unsigned short*)(ws + 46 * MB);   //  4 MiB
  unsigned short* v_tl   = (unsigned short*)(ws + 50 * MB);   //  4 MiB
  float*          retn   = (float*)(ws + 54 * MB);            // 16 MiB (both batches)
  float*          partial= (float*)(ws + 70 * MB);            // 16 MiB (per batch)
  unsigned short* pre_hi = (unsigned short*)(ws + 14 * MB);   //  8 MiB (alias q_h, dead by then)
  unsigned short* pre_lo = (unsigned short*)(ws + 22 * MB);   //  8 MiB (alias q_l)
  float* out = (float*)d_out;

  convert_kernel<<<dim3(24576), 256, 0, stream>>>(x, w1, w2, x_bf, w1t, w2t_hi, w2t_lo);
  for (int b = 0; b < B_; ++b) {
    qkv_kernel<<<dim3(S_ / 64, H_), 256, 0, stream>>>(
        x, wq, bq, wk, bk, wv, theta, q_h, q_l, k_h, k_l, v_th, v_tl, b);
    retention_split_kernel<<<dim3(1024), 256, 0, stream>>>(
        q_h, q_l, k_h, k_l, v_th, v_tl, partial);
    combine_gn_kernel<<<dim3(512), 256, 0, stream>>>(
        partial, gn_w, gn_b, retn, b);
  }
  gemm_gate_kernel<<<dim3(HID_ / 128, (B_ * S_) / 128), 256, 0, stream>>>(
      x_bf, w1t, retn, pre_hi, pre_lo);
  gemm_out_kernel<<<dim3(HID_ / 128, (B_ * S_) / 128), 256, 0, stream>>>(
      pre_hi, pre_lo, w2t_hi, w2t_lo, out);
}